// Round 13
// baseline (464.850 us; speedup 1.0000x reference)
//
#include <hip/hip_runtime.h>
#include <hip/hip_bf16.h>
#include <cstdint>
#include <cstddef>

#define N_NODES 50000
#define N_EDGES 800000
#define IN_DIM 256
#define H1 640
#define H2 320
#define OUT_DIM 128

typedef unsigned short u16;
typedef __attribute__((ext_vector_type(8))) short short8v;   // 8 bf16 = 4 VGPR
typedef __attribute__((ext_vector_type(4))) float float4v;   // MFMA C/D

__device__ __forceinline__ float b2f(u16 u) {
    union { unsigned int i; float f; } v; v.i = ((unsigned int)u) << 16; return v.f;
}
__device__ __forceinline__ u16 f2b(float f) {
    __hip_bfloat16 h = __float2bfloat16(f);
    return *reinterpret_cast<u16*>(&h);
}

// ---------------------------------------------------------------------------
// CSR build (multi-block scan)
// ---------------------------------------------------------------------------

#define SCAN_BLK 256
#define SCAN_NB  ((N_NODES + SCAN_BLK - 1) / SCAN_BLK)   // 196

__global__ void zero2_kernel(int* __restrict__ a, int* __restrict__ b, int n) {
    int i = blockIdx.x * blockDim.x + threadIdx.x;
    if (i < n) { a[i] = 0; b[i] = 0; }
}

__global__ void count_deg_kernel(const int* __restrict__ dst, int* __restrict__ cnt, int nE) {
    int i = blockIdx.x * blockDim.x + threadIdx.x;
    if (i < nE) atomicAdd(&cnt[dst[i]], 1);
}

__global__ __launch_bounds__(SCAN_BLK)
void block_sum_kernel(const int* __restrict__ cnt, int* __restrict__ bsum) {
    __shared__ int red[SCAN_BLK];
    int t = threadIdx.x;
    int i = blockIdx.x * SCAN_BLK + t;
    red[t] = (i < N_NODES) ? cnt[i] : 0;
    __syncthreads();
#pragma unroll
    for (int off = SCAN_BLK / 2; off > 0; off >>= 1) {
        if (t < off) red[t] += red[t + off];
        __syncthreads();
    }
    if (t == 0) bsum[blockIdx.x] = red[0];
}

__global__ __launch_bounds__(SCAN_BLK)
void scan_bsum_kernel(const int* __restrict__ bsum, int* __restrict__ boff) {
    __shared__ int s[SCAN_BLK];
    int t = threadIdx.x;
    s[t] = (t < SCAN_NB) ? bsum[t] : 0;
    __syncthreads();
#pragma unroll
    for (int off = 1; off < SCAN_BLK; off <<= 1) {
        int v = (t >= off) ? s[t - off] : 0;
        __syncthreads();
        s[t] += v;
        __syncthreads();
    }
    if (t < SCAN_NB) boff[t] = (t == 0) ? 0 : s[t - 1];
}

__global__ __launch_bounds__(SCAN_BLK)
void final_scan_kernel(const int* __restrict__ cnt, const int* __restrict__ boff,
                       int* __restrict__ row_ptr, float* __restrict__ inv_deg) {
    __shared__ int s[SCAN_BLK];
    int b = blockIdx.x, t = threadIdx.x;
    int i = b * SCAN_BLK + t;
    int v = (i < N_NODES) ? cnt[i] : 0;
    s[t] = v;
    __syncthreads();
#pragma unroll
    for (int off = 1; off < SCAN_BLK; off <<= 1) {
        int u = (t >= off) ? s[t - off] : 0;
        __syncthreads();
        s[t] += u;
        __syncthreads();
    }
    if (i < N_NODES) {
        int base = boff[b];
        int incl = s[t];
        row_ptr[i] = base + incl - v;
        inv_deg[i] = (v > 0) ? (1.0f / (float)v) : 0.0f;
        if (i == N_NODES - 1) row_ptr[N_NODES] = base + incl;
    }
}

__global__ void scatter_kernel(const int* __restrict__ src, const int* __restrict__ dst,
                               const int* __restrict__ row_ptr, int* __restrict__ cursor,
                               int* __restrict__ csr_src, int nE) {
    int i = blockIdx.x * blockDim.x + threadIdx.x;
    if (i < nE) {
        int d = dst[i];
        int p = atomicAdd(&cursor[d], 1);
        csr_src[row_ptr[d] + p] = src[i];
    }
}

// ---------------------------------------------------------------------------
// f32 -> bf16 cast (vectorized)
// ---------------------------------------------------------------------------

__global__ void cast_kernel(const float4* __restrict__ in, ushort4* __restrict__ out, int n4) {
    int i = blockIdx.x * blockDim.x + threadIdx.x;
    if (i < n4) {
        float4 v = in[i];
        ushort4 o;
        o.x = f2b(v.x); o.y = f2b(v.y); o.z = f2b(v.z); o.w = f2b(v.w);
        out[i] = o;
    }
}

// ---------------------------------------------------------------------------
// Batched weight transpose+cast: all 7 weights in one launch (blockIdx.z).
// in f32 [K][N] -> out bf16 [rowOff + N][K]
// ---------------------------------------------------------------------------

__global__ __launch_bounds__(256)
void transpose_all_kernel(const float* __restrict__ W1s, const float* __restrict__ Wres,
                          const float* __restrict__ W1n, const float* __restrict__ W2n,
                          const float* __restrict__ W2s, const float* __restrict__ W3n,
                          const float* __restrict__ W3s,
                          u16* __restrict__ W1T, u16* __restrict__ W1nT,
                          u16* __restrict__ W23T, u16* __restrict__ W3T) {
    const float* in; u16* out; int K, N, rowOff;
    switch (blockIdx.z) {
        case 0: in = W1s;  out = W1T;  K = 256; N = 640; rowOff = 0;   break;
        case 1: in = Wres; out = W1T;  K = 256; N = 128; rowOff = 640; break;
        case 2: in = W1n;  out = W1nT; K = 256; N = 640; rowOff = 0;   break;
        case 3: in = W2n;  out = W23T; K = 640; N = 320; rowOff = 0;   break;
        case 4: in = W2s;  out = W23T; K = 640; N = 320; rowOff = 320; break;
        case 5: in = W3n;  out = W3T;  K = 320; N = 128; rowOff = 0;   break;
        default: in = W3s; out = W3T;  K = 320; N = 128; rowOff = 128; break;
    }
    int bx = blockIdx.x * 32;   // N direction
    int by = blockIdx.y * 32;   // K direction
    if (bx >= N || by >= K) return;
    __shared__ float t[32][33];
    int x = threadIdx.x;        // 0..31
    int y = threadIdx.y;        // 0..7
#pragma unroll
    for (int i = 0; i < 32; i += 8) {
        int r = by + y + i, c = bx + x;
        if (r < K && c < N) t[y + i][x] = in[(size_t)r * N + c];
    }
    __syncthreads();
#pragma unroll
    for (int i = 0; i < 32; i += 8) {
        int r = bx + y + i, c = by + x;
        if (r < N && c < K) out[(size_t)(rowOff + r) * K + c] = f2b(t[x][y + i]);
    }
}

// ---------------------------------------------------------------------------
// Mean aggregation — block-level lane groups, no LDS, no barriers.
// group g = t/L owns one node (L = D/8 lanes, each a 16B col-slice);
// Edge loop unrolled x4 (4 independent gathers in flight per lane).
// Persistent grid-stride.
// MODE 0: out_bf16 = sum * w
// MODE 1: out_bf16 = elu(sum*w + T_bf16 + bias)
// MODE 2: out_f32  = elu(sum*w + T_f32  + bias)
// ---------------------------------------------------------------------------

#define AGG_GRID 2048

template<int D, int MODE>
__global__ __launch_bounds__(256, 8)
void aggregate_kernel(const u16* __restrict__ h, const int* __restrict__ row_ptr,
                      const int* __restrict__ csr_src, const float* __restrict__ inv_deg,
                      const void* __restrict__ T, const float* __restrict__ bias,
                      void* __restrict__ out) {
    constexpr int L = D / 8;             // lanes per group
    constexpr int GPB = 256 / L;         // groups per block (D=320: 6, 240 thr)
    int t = threadIdx.x;
    int g = t / L, cl = t % L;
    if (g >= GPB) return;                // only trims threads for D=320

    float bv[8];
    if (MODE != 0) {
        const float* bp = bias + cl * 8;
        float4 ba = *(const float4*)bp, bb = *(const float4*)(bp + 4);
        bv[0] = ba.x; bv[1] = ba.y; bv[2] = ba.z; bv[3] = ba.w;
        bv[4] = bb.x; bv[5] = bb.y; bv[6] = bb.z; bv[7] = bb.w;
    }

    const u16* __restrict__ hb = h + cl * 8;
    const int stride = gridDim.x * GPB;
    for (int node = blockIdx.x * GPB + g; node < N_NODES; node += stride) {
        int e0 = row_ptr[node], e1 = row_ptr[node + 1];
        float acc[8];
#pragma unroll
        for (int j = 0; j < 8; ++j) acc[j] = 0.0f;

        for (int e = e0; e < e1; e += 4) {
            int idx[4]; float msk[4];
#pragma unroll
            for (int u = 0; u < 4; ++u) {
                int ee = e + u;
                msk[u] = (ee < e1) ? 1.0f : 0.0f;
                idx[u] = csr_src[(ee < e1) ? ee : e];
            }
            short8v v[4];
#pragma unroll
            for (int u = 0; u < 4; ++u)
                v[u] = *(const short8v*)(hb + (size_t)idx[u] * D);
#pragma unroll
            for (int u = 0; u < 4; ++u)
#pragma unroll
                for (int j = 0; j < 8; ++j)
                    acc[j] += msk[u] * b2f((u16)v[u][j]);
        }

        float w = inv_deg[node];
        if (MODE == 0) {
            short8v o;
#pragma unroll
            for (int j = 0; j < 8; ++j) o[j] = (short)f2b(acc[j] * w);
            *(short8v*)((u16*)out + (size_t)node * D + cl * 8) = o;
        } else if (MODE == 1) {
            short8v tb = *(const short8v*)((const u16*)T + (size_t)node * D + cl * 8);
            short8v o;
#pragma unroll
            for (int j = 0; j < 8; ++j) {
                float x = acc[j] * w + b2f((u16)tb[j]) + bv[j];
                x = (x > 0.0f) ? x : expm1f(x);
                o[j] = (short)f2b(x);
            }
            *(short8v*)((u16*)out + (size_t)node * D + cl * 8) = o;
        } else {
            const float* tp = (const float*)T + (size_t)node * D + cl * 8;
            float4 ta = *(const float4*)tp, tb4 = *(const float4*)(tp + 4);
            float tv[8] = {ta.x, ta.y, ta.z, ta.w, tb4.x, tb4.y, tb4.z, tb4.w};
            float v8[8];
#pragma unroll
            for (int j = 0; j < 8; ++j) {
                float x = acc[j] * w + tv[j] + bv[j];
                v8[j] = (x > 0.0f) ? x : expm1f(x);
            }
            float* op = (float*)out + (size_t)node * D + cl * 8;
            *(float4*)op = make_float4(v8[0], v8[1], v8[2], v8[3]);
            *(float4*)(op + 4) = make_float4(v8[4], v8[5], v8[6], v8[7]);
        }
    }
}

// ---------------------------------------------------------------------------
// MFMA GEMM — r13: 4-buffer ring, issue-3-ahead, steady-state vmcnt(8)
// (T4 deeper: 12 loads in flight/thread, wait only the oldest 4), plus
// T5 s_setprio(1) around the MFMA cluster (structure now has load-issue vs
// MFMA role split, so setprio can arbitrate — m218b).
// Hazards (4-buf): buffer (kt+3)%4 written after the step-kt barrier was
// last read at step kt-1; every wave passed that barrier only after its
// kt-1 reads completed (compiler lgkmcnt before MFMA use). RAW covered by
// own-wave counted vmcnt + barrier (all waves' loads for buf kt landed).
// 2-way-free swizzle cg/sw = x ^ ((row>>1)&3) both sides (r11, verified 0
// conflicts). W pre-transposed bf16 [N][K].
// EPI 0: C0 bf16 = elu(acc + bias)
// EPI 2: split at N0: C0 bf16 raw | C1 bf16 raw
// EPI 3: split at N0: C0 bf16 raw | C1 f32 raw
// EPI 4: split at N0: C0 bf16 elu(+bias) | C1 f32 elu(+bias2)
// Grid 1D with bijective XCD swizzle; N % 128 == 0, K % 32 == 0 (NT >= 8
// for all shapes here), M ragged.
// ---------------------------------------------------------------------------

template<bool DUAL, int EPI>
__global__ __launch_bounds__(256)
void mfma_gemm_kernel(const u16* __restrict__ A0, const u16* __restrict__ A1,
                      const u16* __restrict__ W0T, const u16* __restrict__ W1T,
                      const float* __restrict__ bias, const float* __restrict__ bias2,
                      void* __restrict__ C0, void* __restrict__ C1,
                      int M, int K, int N, int N0, int gx) {
    // bijective XCD swizzle (m204)
    int nwg = gridDim.x;
    int d = blockIdx.x;
    int q = nwg >> 3, r8 = nwg & 7;
    int xcd = d & 7, idx = d >> 3;
    int flat = (xcd < r8 ? xcd * (q + 1) : r8 * (q + 1) + (xcd - r8) * q) + idx;
    int bxt = flat % gx, byt = flat / gx;

    int tid = threadIdx.x;
    int wid = tid >> 6;
    int lane = tid & 63;
    int lr = lane & 15;        // row (A) / col (B) within fragment
    int lb = lane >> 4;        // k-chunk 0..3 (8 elems = 16 B each)
    int wr = wid >> 1;         // wave row (M dir)
    int wc = wid & 1;          // wave col (N dir)

    int bm = byt * 128;        // block row base
    int bn = bxt * 128;        // block col base

    // LDS: 4 buffers x [A 4096 u16 | B 4096 u16] = 64 KB
    __shared__ u16 smem[4 * 8192];

    const int NT0 = K >> 5;                    // K-steps per stream (>= 8 here)
    const int NT = DUAL ? (NT0 * 2) : NT0;

    // ---- hoisted staging state (per thread: 2 A-chunks + 2 B-chunks) ----
    int c  = tid & 3;                          // 16B chunk-in-row
    int rr = tid >> 2;                         // LDS row 0..63 (chunk1: +64)
    int cg = c ^ ((rr >> 1) & 3);              // 2-way-free source swizzle
    int rA0 = bm + rr;      if (rA0 > M - 1) rA0 = M - 1;
    int rA1 = bm + rr + 64; if (rA1 > M - 1) rA1 = M - 1;
    const u16* pA0 = A0 + (size_t)rA0 * K + cg * 8;
    const u16* pA1 = A0 + (size_t)rA1 * K + cg * 8;
    const u16* pB0 = W0T + (size_t)(bn + rr) * K + cg * 8;
    const u16* pB1 = W0T + (size_t)(bn + rr + 64) * K + cg * 8;
    int dA0 = tid * 8, dA1 = (tid + 256) * 8;  // LDS u16 offsets (A); B adds 4096

    auto issue = [&](int buf) {
        u16* ab = smem + buf * 8192;
        __builtin_amdgcn_global_load_lds(
            (const __attribute__((address_space(1))) void*)pA0,
            (__attribute__((address_space(3))) void*)(ab + dA0), 16, 0, 0);
        __builtin_amdgcn_global_load_lds(
            (const __attribute__((address_space(1))) void*)pA1,
            (__attribute__((address_space(3))) void*)(ab + dA1), 16, 0, 0);
        __builtin_amdgcn_global_load_lds(
            (const __attribute__((address_space(1))) void*)pB0,
            (__attribute__((address_space(3))) void*)(ab + 4096 + dA0), 16, 0, 0);
        __builtin_amdgcn_global_load_lds(
            (const __attribute__((address_space(1))) void*)pB1,
            (__attribute__((address_space(3))) void*)(ab + 4096 + dA1), 16, 0, 0);
        pA0 += 32; pA1 += 32; pB0 += 32; pB1 += 32;
    };

    float4v acc[4][4] = {};

    // prologue: stage K-steps 0,1,2 into buffers 0,1,2 (NT >= 8 always here;
    // DUAL seam NT0 >= 8 so the prologue never crosses the stream seam)
    issue(0);
    issue(1);
    issue(2);

    int sw = lb ^ ((lr >> 1) & 3);             // 2-way-free read swizzle
    int rdA = (wr * 64 + lr) * 32 + sw * 8;    // + i*512 per fragment
    int rdB = 4096 + (wc * 64 + lr) * 32 + sw * 8;

    for (int kt = 0; kt < NT; ++kt) {
        // counted vmcnt: wait only for the oldest staged buffer (this step's).
        if (kt + 2 < NT)      asm volatile("s_waitcnt vmcnt(8)" ::: "memory");
        else if (kt + 1 < NT) asm volatile("s_waitcnt vmcnt(4)" ::: "memory");
        else                  asm volatile("s_waitcnt vmcnt(0)" ::: "memory");
        __builtin_amdgcn_s_barrier();          // all waves' loads for this buf landed

        const u16* base = smem + (kt & 3) * 8192;
        short8v af[4], bf[4];
#pragma unroll
        for (int i = 0; i < 4; ++i)
            af[i] = *(const short8v*)(base + rdA + i * 512);
#pragma unroll
        for (int j = 0; j < 4; ++j)
            bf[j] = *(const short8v*)(base + rdB + j * 512);

        // stage K-step kt+3 into buffer (kt+3)%4 (last read at iter kt-1;
        // the barrier above proves all waves are past those reads)
        if (kt + 3 < NT) {
            if (DUAL && kt + 3 == NT0) {       // stream seam: reset pointers
                pA0 = A1 + (size_t)rA0 * K + cg * 8;
                pA1 = A1 + (size_t)rA1 * K + cg * 8;
                pB0 = W1T + (size_t)(bn + rr) * K + cg * 8;
                pB1 = W1T + (size_t)(bn + rr + 64) * K + cg * 8;
            }
            issue((kt + 3) & 3);
        }

        __builtin_amdgcn_s_setprio(1);
#pragma unroll
        for (int i = 0; i < 4; ++i)
#pragma unroll
            for (int j = 0; j < 4; ++j)
                acc[i][j] = __builtin_amdgcn_mfma_f32_16x16x32_bf16(
                    af[i], bf[j], acc[i][j], 0, 0, 0);
        __builtin_amdgcn_s_setprio(0);
    }

    // epilogue: C[bm + wr*64 + i*16 + lb*4 + rr2][bn + wc*64 + j*16 + lr]
    int bmw = bm + wr * 64, bnw = bn + wc * 64;
    if (EPI == 0) {
        float bi[4];
#pragma unroll
        for (int j = 0; j < 4; ++j) bi[j] = bias[bnw + j * 16 + lr];
#pragma unroll
        for (int i = 0; i < 4; ++i) {
#pragma unroll
            for (int rr2 = 0; rr2 < 4; ++rr2) {
                int row = bmw + i * 16 + lb * 4 + rr2;
                if (row >= M) continue;
#pragma unroll
                for (int j = 0; j < 4; ++j) {
                    int col = bnw + j * 16 + lr;
                    float v = acc[i][j][rr2] + bi[j];
                    v = (v > 0.0f) ? v : expm1f(v);
                    ((u16*)C0)[(size_t)row * N + col] = f2b(v);
                }
            }
        }
    } else if (EPI == 4) {
        // tiles never straddle N0 (N0 % 128 == 0)
        bool resTile = (bnw >= N0);
        int N1 = N - N0;
        float bi[4];
#pragma unroll
        for (int j = 0; j < 4; ++j) {
            int cidx = bnw + j * 16 + lr;
            bi[j] = resTile ? bias2[cidx - N0] : bias[cidx];
        }
#pragma unroll
        for (int i = 0; i < 4; ++i) {
#pragma unroll
            for (int rr2 = 0; rr2 < 4; ++rr2) {
                int row = bmw + i * 16 + lb * 4 + rr2;
                if (row >= M) continue;
#pragma unroll
                for (int j = 0; j < 4; ++j) {
                    int col = bnw + j * 16 + lr;
                    float v = acc[i][j][rr2] + bi[j];
                    v = (v > 0.0f) ? v : expm1f(v);
                    if (resTile) ((float*)C1)[(size_t)row * N1 + (col - N0)] = v;
                    else         ((u16*)C0)[(size_t)row * N0 + col] = f2b(v);
                }
            }
        }
    } else {
        int N1 = N - N0;
#pragma unroll
        for (int i = 0; i < 4; ++i) {
#pragma unroll
            for (int rr2 = 0; rr2 < 4; ++rr2) {
                int row = bmw + i * 16 + lb * 4 + rr2;
                if (row >= M) continue;
#pragma unroll
                for (int j = 0; j < 4; ++j) {
                    int col = bnw + j * 16 + lr;
                    float v = acc[i][j][rr2];
                    if (col < N0) {
                        ((u16*)C0)[(size_t)row * N0 + col] = f2b(v);
                    } else {
                        int c1 = col - N0;
                        if (EPI == 3) ((float*)C1)[(size_t)row * N1 + c1] = v;
                        else          ((u16*)C1)[(size_t)row * N1 + c1] = f2b(v);
                    }
                }
            }
        }
    }
}

// ---------------------------------------------------------------------------

extern "C" void kernel_launch(void* const* d_in, const int* in_sizes, int n_in,
                              void* d_out, int out_size, void* d_ws, size_t ws_size,
                              hipStream_t stream) {
    const float* features = (const float*)d_in[0];
    const int*   edge_src = (const int*)d_in[1];
    const int*   edge_dst = (const int*)d_in[2];
    const float* W1s = (const float*)d_in[3];
    const float* W1n = (const float*)d_in[4];
    const float* b1  = (const float*)d_in[5];
    const float* W2s = (const float*)d_in[6];
    const float* W2n = (const float*)d_in[7];
    const float* b2  = (const float*)d_in[8];
    const float* W3s = (const float*)d_in[9];
    const float* W3n = (const float*)d_in[10];
    const float* b3  = (const float*)d_in[11];
    const float* Wres = (const float*)d_in[12];
    const float* bres = (const float*)d_in[13];

    float* out_x   = (float*)d_out;
    float* out_res = out_x + (size_t)N_NODES * OUT_DIM;

    // ---- workspace layout ----
    size_t off = 0;
    auto carve = [&](size_t bytes) {
        size_t p = off;
        off += (bytes + 255) & ~(size_t)255;
        return p;
    };
    size_t o_cnt     = carve((size_t)N_NODES * 4);
    size_t o_rowptr  = carve((size_t)(N_NODES + 1) * 4);
    size_t o_cursor  = carve((size_t)N_NODES * 4);
    size_t o_invdeg  = carve((size_t)N_NODES * 4);
    size_t o_csr     = carve((size_t)N_EDGES * 4);
    size_t o_bsum    = carve((size_t)SCAN_NB * 4);
    size_t o_boff    = carve((size_t)SCAN_NB * 4);
    size_t o_w1   = carve((size_t)(H1 + OUT_DIM) * IN_DIM * 2);   // [W1s|Wres]T : 768 x 256
    size_t o_w1n  = carve((size_t)(H1 + OUT_DIM) * IN_DIM * 2);   // [W1n|0]T    : 768 x 256
    size_t o_w23  = carve((size_t)H1 * (H2 + H2) * 2);            // [W2n|W2s]T  : 640 x 640
    size_t o_w3   = carve((size_t)H2 * (OUT_DIM * 2) * 2);        // [W3n|W3s]T  : 256 x 320
    size_t o_regA = carve((size_t)N_NODES * (IN_DIM + IN_DIM) * 2);  // fX+aggF ; later x2
    size_t o_regB = carve((size_t)N_NODES * H1 * 2);                 // x1 ; later Y3+T3(f32)
    size_t o_regC = carve((size_t)N_NODES * H2 * 2);                 // Y2
    size_t o_regD = carve((size_t)N_NODES * H2 * 2);                 // T2
    size_t REQUIRED = off;
    if (ws_size < REQUIRED) return;

    char* W = (char*)d_ws;
    int*   cnt     = (int*)(W + o_cnt);
    int*   row_ptr = (int*)(W + o_rowptr);
    int*   cursor  = (int*)(W + o_cursor);
    float* inv_deg = (float*)(W + o_invdeg);
    int*   csr_src = (int*)(W + o_csr);
    int*   bsum    = (int*)(W + o_bsum);
    int*   boff    = (int*)(W + o_boff);
    u16* W1T  = (u16*)(W + o_w1);
    u16* W1nT = (u16*)(W + o_w1n);
    u16* W23T = (u16*)(W + o_w23);
    u16* W3T  = (u16*)(W + o_w3);
    u16* fX   = (u16*)(W + o_regA);
    u16* aggF = fX + (size_t)N_NODES * IN_DIM;
    u16* x2   = (u16*)(W + o_regA);                 // aliases fX+aggF (dead by then)
    u16* x1   = (u16*)(W + o_regB);
    u16* Y3   = (u16*)(W + o_regB);                 // aliases x1 (dead by then)
    float* T3 = (float*)(W + o_regB + (size_t)N_NODES * OUT_DIM * 2);
    u16* Y2   = (u16*)(W + o_regC);
    u16* T2   = (u16*)(W + o_regD);

    const int mt = (N_NODES + 127) / 128;

    // ---- CSR build (multi-block scan) ----
    zero2_kernel<<<(N_NODES + 255) / 256, 256, 0, stream>>>(cnt, cursor, N_NODES);
    count_deg_kernel<<<(N_EDGES + 255) / 256, 256, 0, stream>>>(edge_dst, cnt, N_EDGES);
    block_sum_kernel<<<SCAN_NB, SCAN_BLK, 0, stream>>>(cnt, bsum);
    scan_bsum_kernel<<<1, SCAN_BLK, 0, stream>>>(bsum, boff);
    final_scan_kernel<<<SCAN_NB, SCAN_BLK, 0, stream>>>(cnt, boff, row_ptr, inv_deg);
    scatter_kernel<<<(N_EDGES + 255) / 256, 256, 0, stream>>>(edge_src, edge_dst, row_ptr,
                                                              cursor, csr_src, N_EDGES);

    // ---- casts / transposes ----
    {
        int n4 = N_NODES * IN_DIM / 4;
        cast_kernel<<<(n4 + 255) / 256, 256, 0, stream>>>((const float4*)features,
                                                          (ushort4*)fX, n4);
    }
    {
        // zero the [W1n|0] pad rows (rows 640..767 of W1nT: 128*256 u16 = 8192 ints)
        int* pad = (int*)(W1nT + (size_t)H1 * IN_DIM);
        zero2_kernel<<<(8192 + 255) / 256, 256, 0, stream>>>(pad, pad, 8192);
        dim3 b(32, 8), g(20, 20, 7);
        transpose_all_kernel<<<g, b, 0, stream>>>(W1s, Wres, W1n, W2n, W2s, W3n, W3s,
                                                  W1T, W1nT, W23T, W3T);
    }

    // ---- layer 1 + residual (merged):
    //   [x1|res] = elu( fX@[W1s|Wres] + aggF@[W1n|0] + [b1|bres] ) ----
    aggregate_kernel<IN_DIM, 0><<<AGG_GRID, 256, 0, stream>>>(
        fX, row_ptr, csr_src, inv_deg, nullptr, nullptr, aggF);
    mfma_gemm_kernel<true, 4><<<((H1 + OUT_DIM) / 128) * mt, 256, 0, stream>>>(
        fX, aggF, W1T, W1nT, b1, bres, x1, out_res,
        N_NODES, IN_DIM, H1 + OUT_DIM, H1, (H1 + OUT_DIM) / 128);

    // ---- layer 2: [Y2|T2] = x1@[W2n|W2s]; x2 = elu(mean(Y2) + T2 + b2) ----
    mfma_gemm_kernel<false, 2><<<((H2 * 2) / 128) * mt, 256, 0, stream>>>(
        x1, nullptr, W23T, nullptr, nullptr, nullptr, Y2, T2,
        N_NODES, H1, H2 * 2, H2, (H2 * 2) / 128);
    aggregate_kernel<H2, 1><<<AGG_GRID, 256, 0, stream>>>(
        Y2, row_ptr, csr_src, inv_deg, T2, b2, x2);

    // ---- layer 3: [Y3|T3] = x2@[W3n|W3s]; out_x = elu(mean(Y3) + T3 + b3) ----
    mfma_gemm_kernel<false, 3><<<((OUT_DIM * 2) / 128) * mt, 256, 0, stream>>>(
        x2, nullptr, W3T, nullptr, nullptr, nullptr, Y3, T3,
        N_NODES, H2, OUT_DIM * 2, OUT_DIM, (OUT_DIM * 2) / 128);
    aggregate_kernel<OUT_DIM, 2><<<AGG_GRID, 256, 0, stream>>>(
        Y3, row_ptr, csr_src, inv_deg, T3, b3, out_x);
}

// Round 14
// 444.532 us; speedup vs baseline: 1.0457x; 1.0457x over previous
//
#include <hip/hip_runtime.h>
#include <hip/hip_bf16.h>
#include <cstdint>
#include <cstddef>

#define N_NODES 50000
#define N_EDGES 800000
#define IN_DIM 256
#define H1 640
#define H2 320
#define OUT_DIM 128

typedef unsigned short u16;
typedef __attribute__((ext_vector_type(8))) short short8v;   // 8 bf16 = 4 VGPR
typedef __attribute__((ext_vector_type(4))) float float4v;   // MFMA C/D

__device__ __forceinline__ float b2f(u16 u) {
    union { unsigned int i; float f; } v; v.i = ((unsigned int)u) << 16; return v.f;
}
__device__ __forceinline__ u16 f2b(float f) {
    __hip_bfloat16 h = __float2bfloat16(f);
    return *reinterpret_cast<u16*>(&h);
}

// ---------------------------------------------------------------------------
// CSR build (multi-block scan)
// ---------------------------------------------------------------------------

#define SCAN_BLK 256
#define SCAN_NB  ((N_NODES + SCAN_BLK - 1) / SCAN_BLK)   // 196

__global__ void zero2_kernel(int* __restrict__ a, int* __restrict__ b, int n) {
    int i = blockIdx.x * blockDim.x + threadIdx.x;
    if (i < n) { a[i] = 0; b[i] = 0; }
}

__global__ void count_deg_kernel(const int* __restrict__ dst, int* __restrict__ cnt, int nE) {
    int i = blockIdx.x * blockDim.x + threadIdx.x;
    if (i < nE) atomicAdd(&cnt[dst[i]], 1);
}

__global__ __launch_bounds__(SCAN_BLK)
void block_sum_kernel(const int* __restrict__ cnt, int* __restrict__ bsum) {
    __shared__ int red[SCAN_BLK];
    int t = threadIdx.x;
    int i = blockIdx.x * SCAN_BLK + t;
    red[t] = (i < N_NODES) ? cnt[i] : 0;
    __syncthreads();
#pragma unroll
    for (int off = SCAN_BLK / 2; off > 0; off >>= 1) {
        if (t < off) red[t] += red[t + off];
        __syncthreads();
    }
    if (t == 0) bsum[blockIdx.x] = red[0];
}

__global__ __launch_bounds__(SCAN_BLK)
void scan_bsum_kernel(const int* __restrict__ bsum, int* __restrict__ boff) {
    __shared__ int s[SCAN_BLK];
    int t = threadIdx.x;
    s[t] = (t < SCAN_NB) ? bsum[t] : 0;
    __syncthreads();
#pragma unroll
    for (int off = 1; off < SCAN_BLK; off <<= 1) {
        int v = (t >= off) ? s[t - off] : 0;
        __syncthreads();
        s[t] += v;
        __syncthreads();
    }
    if (t < SCAN_NB) boff[t] = (t == 0) ? 0 : s[t - 1];
}

__global__ __launch_bounds__(SCAN_BLK)
void final_scan_kernel(const int* __restrict__ cnt, const int* __restrict__ boff,
                       int* __restrict__ row_ptr, float* __restrict__ inv_deg) {
    __shared__ int s[SCAN_BLK];
    int b = blockIdx.x, t = threadIdx.x;
    int i = b * SCAN_BLK + t;
    int v = (i < N_NODES) ? cnt[i] : 0;
    s[t] = v;
    __syncthreads();
#pragma unroll
    for (int off = 1; off < SCAN_BLK; off <<= 1) {
        int u = (t >= off) ? s[t - off] : 0;
        __syncthreads();
        s[t] += u;
        __syncthreads();
    }
    if (i < N_NODES) {
        int base = boff[b];
        int incl = s[t];
        row_ptr[i] = base + incl - v;
        inv_deg[i] = (v > 0) ? (1.0f / (float)v) : 0.0f;
        if (i == N_NODES - 1) row_ptr[N_NODES] = base + incl;
    }
}

__global__ void scatter_kernel(const int* __restrict__ src, const int* __restrict__ dst,
                               const int* __restrict__ row_ptr, int* __restrict__ cursor,
                               int* __restrict__ csr_src, int nE) {
    int i = blockIdx.x * blockDim.x + threadIdx.x;
    if (i < nE) {
        int d = dst[i];
        int p = atomicAdd(&cursor[d], 1);
        csr_src[row_ptr[d] + p] = src[i];
    }
}

// ---------------------------------------------------------------------------
// f32 -> bf16 cast (vectorized)
// ---------------------------------------------------------------------------

__global__ void cast_kernel(const float4* __restrict__ in, ushort4* __restrict__ out, int n4) {
    int i = blockIdx.x * blockDim.x + threadIdx.x;
    if (i < n4) {
        float4 v = in[i];
        ushort4 o;
        o.x = f2b(v.x); o.y = f2b(v.y); o.z = f2b(v.z); o.w = f2b(v.w);
        out[i] = o;
    }
}

// ---------------------------------------------------------------------------
// Batched weight transpose+cast: all 7 weights in one launch (blockIdx.z).
// in f32 [K][N] -> out bf16 [rowOff + N][K]
// ---------------------------------------------------------------------------

__global__ __launch_bounds__(256)
void transpose_all_kernel(const float* __restrict__ W1s, const float* __restrict__ Wres,
                          const float* __restrict__ W1n, const float* __restrict__ W2n,
                          const float* __restrict__ W2s, const float* __restrict__ W3n,
                          const float* __restrict__ W3s,
                          u16* __restrict__ W1T, u16* __restrict__ W1nT,
                          u16* __restrict__ W23T, u16* __restrict__ W3T) {
    const float* in; u16* out; int K, N, rowOff;
    switch (blockIdx.z) {
        case 0: in = W1s;  out = W1T;  K = 256; N = 640; rowOff = 0;   break;
        case 1: in = Wres; out = W1T;  K = 256; N = 128; rowOff = 640; break;
        case 2: in = W1n;  out = W1nT; K = 256; N = 640; rowOff = 0;   break;
        case 3: in = W2n;  out = W23T; K = 640; N = 320; rowOff = 0;   break;
        case 4: in = W2s;  out = W23T; K = 640; N = 320; rowOff = 320; break;
        case 5: in = W3n;  out = W3T;  K = 320; N = 128; rowOff = 0;   break;
        default: in = W3s; out = W3T;  K = 320; N = 128; rowOff = 128; break;
    }
    int bx = blockIdx.x * 32;   // N direction
    int by = blockIdx.y * 32;   // K direction
    if (bx >= N || by >= K) return;
    __shared__ float t[32][33];
    int x = threadIdx.x;        // 0..31
    int y = threadIdx.y;        // 0..7
#pragma unroll
    for (int i = 0; i < 32; i += 8) {
        int r = by + y + i, c = bx + x;
        if (r < K && c < N) t[y + i][x] = in[(size_t)r * N + c];
    }
    __syncthreads();
#pragma unroll
    for (int i = 0; i < 32; i += 8) {
        int r = bx + y + i, c = by + x;
        if (r < N && c < K) out[(size_t)(rowOff + r) * K + c] = f2b(t[x][y + i]);
    }
}

// ---------------------------------------------------------------------------
// Mean aggregation — block-level lane groups, no LDS, no barriers.
// group g = t/L owns one node (L = D/8 lanes, each a 16B col-slice);
// Edge loop unrolled x4 (4 independent gathers in flight per lane).
// Persistent grid-stride.
// MODE 0: out_bf16 = sum * w
// MODE 1: out_bf16 = elu(sum*w + T_bf16 + bias)
// MODE 2: out_f32  = elu(sum*w + T_f32  + bias)
// ---------------------------------------------------------------------------

#define AGG_GRID 2048

template<int D, int MODE>
__global__ __launch_bounds__(256, 8)
void aggregate_kernel(const u16* __restrict__ h, const int* __restrict__ row_ptr,
                      const int* __restrict__ csr_src, const float* __restrict__ inv_deg,
                      const void* __restrict__ T, const float* __restrict__ bias,
                      void* __restrict__ out) {
    constexpr int L = D / 8;             // lanes per group
    constexpr int GPB = 256 / L;         // groups per block (D=320: 6, 240 thr)
    int t = threadIdx.x;
    int g = t / L, cl = t % L;
    if (g >= GPB) return;                // only trims threads for D=320

    float bv[8];
    if (MODE != 0) {
        const float* bp = bias + cl * 8;
        float4 ba = *(const float4*)bp, bb = *(const float4*)(bp + 4);
        bv[0] = ba.x; bv[1] = ba.y; bv[2] = ba.z; bv[3] = ba.w;
        bv[4] = bb.x; bv[5] = bb.y; bv[6] = bb.z; bv[7] = bb.w;
    }

    const u16* __restrict__ hb = h + cl * 8;
    const int stride = gridDim.x * GPB;
    for (int node = blockIdx.x * GPB + g; node < N_NODES; node += stride) {
        int e0 = row_ptr[node], e1 = row_ptr[node + 1];
        float acc[8];
#pragma unroll
        for (int j = 0; j < 8; ++j) acc[j] = 0.0f;

        for (int e = e0; e < e1; e += 4) {
            int idx[4]; float msk[4];
#pragma unroll
            for (int u = 0; u < 4; ++u) {
                int ee = e + u;
                msk[u] = (ee < e1) ? 1.0f : 0.0f;
                idx[u] = csr_src[(ee < e1) ? ee : e];
            }
            short8v v[4];
#pragma unroll
            for (int u = 0; u < 4; ++u)
                v[u] = *(const short8v*)(hb + (size_t)idx[u] * D);
#pragma unroll
            for (int u = 0; u < 4; ++u)
#pragma unroll
                for (int j = 0; j < 8; ++j)
                    acc[j] += msk[u] * b2f((u16)v[u][j]);
        }

        float w = inv_deg[node];
        if (MODE == 0) {
            short8v o;
#pragma unroll
            for (int j = 0; j < 8; ++j) o[j] = (short)f2b(acc[j] * w);
            *(short8v*)((u16*)out + (size_t)node * D + cl * 8) = o;
        } else if (MODE == 1) {
            short8v tb = *(const short8v*)((const u16*)T + (size_t)node * D + cl * 8);
            short8v o;
#pragma unroll
            for (int j = 0; j < 8; ++j) {
                float x = acc[j] * w + b2f((u16)tb[j]) + bv[j];
                x = (x > 0.0f) ? x : expm1f(x);
                o[j] = (short)f2b(x);
            }
            *(short8v*)((u16*)out + (size_t)node * D + cl * 8) = o;
        } else {
            const float* tp = (const float*)T + (size_t)node * D + cl * 8;
            float4 ta = *(const float4*)tp, tb4 = *(const float4*)(tp + 4);
            float tv[8] = {ta.x, ta.y, ta.z, ta.w, tb4.x, tb4.y, tb4.z, tb4.w};
            float v8[8];
#pragma unroll
            for (int j = 0; j < 8; ++j) {
                float x = acc[j] * w + tv[j] + bv[j];
                v8[j] = (x > 0.0f) ? x : expm1f(x);
            }
            float* op = (float*)out + (size_t)node * D + cl * 8;
            *(float4*)op = make_float4(v8[0], v8[1], v8[2], v8[3]);
            *(float4*)(op + 4) = make_float4(v8[4], v8[5], v8[6], v8[7]);
        }
    }
}

// ---------------------------------------------------------------------------
// MFMA GEMM — r14: REVERT to r12's 3-buffer ring / 48 KB LDS (r13's 4-buf
// 64 KB dropped occupancy 27->19% and regressed 86.6->101 µs; the occupancy
// cliff on this structure is LDS <= 48 KB). Counted vmcnt: issue 2 ahead,
// wait vmcnt(4) steady-state, vmcnt(0) only on the last step. Only delta vs
// r12: T5 s_setprio(1) around the MFMA cluster (isolated this round).
// Hazards: RAW = own counted vmcnt + barrier; WAR = buffer (kt+2)%3 written
// after the step-kt barrier was last read at step kt-1, and every wave
// passed that barrier only after its kt-1 reads completed.
// 2-way-free swizzle cg/sw = x ^ ((row>>1)&3) both sides (verified 0
// conflicts, r11). W pre-transposed bf16 [N][K].
// EPI 0: C0 bf16 = elu(acc + bias)
// EPI 2: split at N0: C0 bf16 raw | C1 bf16 raw
// EPI 3: split at N0: C0 bf16 raw | C1 f32 raw
// EPI 4: split at N0: C0 bf16 elu(+bias) | C1 f32 elu(+bias2)
// Grid 1D with bijective XCD swizzle; N % 128 == 0, K % 32 == 0, M ragged.
// ---------------------------------------------------------------------------

template<bool DUAL, int EPI>
__global__ __launch_bounds__(256)
void mfma_gemm_kernel(const u16* __restrict__ A0, const u16* __restrict__ A1,
                      const u16* __restrict__ W0T, const u16* __restrict__ W1T,
                      const float* __restrict__ bias, const float* __restrict__ bias2,
                      void* __restrict__ C0, void* __restrict__ C1,
                      int M, int K, int N, int N0, int gx) {
    // bijective XCD swizzle (m204)
    int nwg = gridDim.x;
    int d = blockIdx.x;
    int q = nwg >> 3, r8 = nwg & 7;
    int xcd = d & 7, idx = d >> 3;
    int flat = (xcd < r8 ? xcd * (q + 1) : r8 * (q + 1) + (xcd - r8) * q) + idx;
    int bxt = flat % gx, byt = flat / gx;

    int tid = threadIdx.x;
    int wid = tid >> 6;
    int lane = tid & 63;
    int lr = lane & 15;        // row (A) / col (B) within fragment
    int lb = lane >> 4;        // k-chunk 0..3 (8 elems = 16 B each)
    int wr = wid >> 1;         // wave row (M dir)
    int wc = wid & 1;          // wave col (N dir)

    int bm = byt * 128;        // block row base
    int bn = bxt * 128;        // block col base

    // LDS: 3 buffers x [A 4096 u16 | B 4096 u16] = 48 KB (3 blocks/CU)
    __shared__ u16 smem[3 * 8192];

    const int NT0 = K >> 5;                    // K-steps per stream
    const int NT = DUAL ? (NT0 * 2) : NT0;

    // ---- hoisted staging state (per thread: 2 A-chunks + 2 B-chunks) ----
    int c  = tid & 3;                          // 16B chunk-in-row
    int rr = tid >> 2;                         // LDS row 0..63 (chunk1: +64)
    int cg = c ^ ((rr >> 1) & 3);              // 2-way-free source swizzle
    int rA0 = bm + rr;      if (rA0 > M - 1) rA0 = M - 1;
    int rA1 = bm + rr + 64; if (rA1 > M - 1) rA1 = M - 1;
    const u16* pA0 = A0 + (size_t)rA0 * K + cg * 8;
    const u16* pA1 = A0 + (size_t)rA1 * K + cg * 8;
    const u16* pB0 = W0T + (size_t)(bn + rr) * K + cg * 8;
    const u16* pB1 = W0T + (size_t)(bn + rr + 64) * K + cg * 8;
    int dA0 = tid * 8, dA1 = (tid + 256) * 8;  // LDS u16 offsets (A); B adds 4096

    auto issue = [&](int buf) {
        u16* ab = smem + buf * 8192;
        __builtin_amdgcn_global_load_lds(
            (const __attribute__((address_space(1))) void*)pA0,
            (__attribute__((address_space(3))) void*)(ab + dA0), 16, 0, 0);
        __builtin_amdgcn_global_load_lds(
            (const __attribute__((address_space(1))) void*)pA1,
            (__attribute__((address_space(3))) void*)(ab + dA1), 16, 0, 0);
        __builtin_amdgcn_global_load_lds(
            (const __attribute__((address_space(1))) void*)pB0,
            (__attribute__((address_space(3))) void*)(ab + 4096 + dA0), 16, 0, 0);
        __builtin_amdgcn_global_load_lds(
            (const __attribute__((address_space(1))) void*)pB1,
            (__attribute__((address_space(3))) void*)(ab + 4096 + dA1), 16, 0, 0);
        pA0 += 32; pA1 += 32; pB0 += 32; pB1 += 32;
    };

    float4v acc[4][4] = {};

    // prologue: stage K-steps 0 and 1 into buffers 0 and 1
    issue(0);
    if (NT > 1) issue(1);

    int sw = lb ^ ((lr >> 1) & 3);             // 2-way-free read swizzle
    int rdA = (wr * 64 + lr) * 32 + sw * 8;    // + i*512 per fragment
    int rdB = 4096 + (wc * 64 + lr) * 32 + sw * 8;

    for (int kt = 0; kt < NT; ++kt) {
        // counted vmcnt: wait only for the buffer we're about to read.
        if (kt + 1 < NT) asm volatile("s_waitcnt vmcnt(4)" ::: "memory");
        else             asm volatile("s_waitcnt vmcnt(0)" ::: "memory");
        __builtin_amdgcn_s_barrier();          // all waves' loads for this buf landed

        const u16* base = smem + (kt % 3) * 8192;
        short8v af[4], bf[4];
#pragma unroll
        for (int i = 0; i < 4; ++i)
            af[i] = *(const short8v*)(base + rdA + i * 512);
#pragma unroll
        for (int j = 0; j < 4; ++j)
            bf[j] = *(const short8v*)(base + rdB + j * 512);

        // stage K-step kt+2 into the buffer last read at iter kt-1
        if (kt + 2 < NT) {
            if (DUAL && kt + 2 == NT0) {       // stream seam: reset pointers
                pA0 = A1 + (size_t)rA0 * K + cg * 8;
                pA1 = A1 + (size_t)rA1 * K + cg * 8;
                pB0 = W1T + (size_t)(bn + rr) * K + cg * 8;
                pB1 = W1T + (size_t)(bn + rr + 64) * K + cg * 8;
            }
            issue((kt + 2) % 3);
        }

        __builtin_amdgcn_s_setprio(1);
#pragma unroll
        for (int i = 0; i < 4; ++i)
#pragma unroll
            for (int j = 0; j < 4; ++j)
                acc[i][j] = __builtin_amdgcn_mfma_f32_16x16x32_bf16(
                    af[i], bf[j], acc[i][j], 0, 0, 0);
        __builtin_amdgcn_s_setprio(0);
    }

    // epilogue: C[bm + wr*64 + i*16 + lb*4 + rr2][bn + wc*64 + j*16 + lr]
    int bmw = bm + wr * 64, bnw = bn + wc * 64;
    if (EPI == 0) {
        float bi[4];
#pragma unroll
        for (int j = 0; j < 4; ++j) bi[j] = bias[bnw + j * 16 + lr];
#pragma unroll
        for (int i = 0; i < 4; ++i) {
#pragma unroll
            for (int rr2 = 0; rr2 < 4; ++rr2) {
                int row = bmw + i * 16 + lb * 4 + rr2;
                if (row >= M) continue;
#pragma unroll
                for (int j = 0; j < 4; ++j) {
                    int col = bnw + j * 16 + lr;
                    float v = acc[i][j][rr2] + bi[j];
                    v = (v > 0.0f) ? v : expm1f(v);
                    ((u16*)C0)[(size_t)row * N + col] = f2b(v);
                }
            }
        }
    } else if (EPI == 4) {
        // tiles never straddle N0 (N0 % 128 == 0)
        bool resTile = (bnw >= N0);
        int N1 = N - N0;
        float bi[4];
#pragma unroll
        for (int j = 0; j < 4; ++j) {
            int cidx = bnw + j * 16 + lr;
            bi[j] = resTile ? bias2[cidx - N0] : bias[cidx];
        }
#pragma unroll
        for (int i = 0; i < 4; ++i) {
#pragma unroll
            for (int rr2 = 0; rr2 < 4; ++rr2) {
                int row = bmw + i * 16 + lb * 4 + rr2;
                if (row >= M) continue;
#pragma unroll
                for (int j = 0; j < 4; ++j) {
                    int col = bnw + j * 16 + lr;
                    float v = acc[i][j][rr2] + bi[j];
                    v = (v > 0.0f) ? v : expm1f(v);
                    if (resTile) ((float*)C1)[(size_t)row * N1 + (col - N0)] = v;
                    else         ((u16*)C0)[(size_t)row * N0 + col] = f2b(v);
                }
            }
        }
    } else {
        int N1 = N - N0;
#pragma unroll
        for (int i = 0; i < 4; ++i) {
#pragma unroll
            for (int rr2 = 0; rr2 < 4; ++rr2) {
                int row = bmw + i * 16 + lb * 4 + rr2;
                if (row >= M) continue;
#pragma unroll
                for (int j = 0; j < 4; ++j) {
                    int col = bnw + j * 16 + lr;
                    float v = acc[i][j][rr2];
                    if (col < N0) {
                        ((u16*)C0)[(size_t)row * N0 + col] = f2b(v);
                    } else {
                        int c1 = col - N0;
                        if (EPI == 3) ((float*)C1)[(size_t)row * N1 + c1] = v;
                        else          ((u16*)C1)[(size_t)row * N1 + c1] = f2b(v);
                    }
                }
            }
        }
    }
}

// ---------------------------------------------------------------------------

extern "C" void kernel_launch(void* const* d_in, const int* in_sizes, int n_in,
                              void* d_out, int out_size, void* d_ws, size_t ws_size,
                              hipStream_t stream) {
    const float* features = (const float*)d_in[0];
    const int*   edge_src = (const int*)d_in[1];
    const int*   edge_dst = (const int*)d_in[2];
    const float* W1s = (const float*)d_in[3];
    const float* W1n = (const float*)d_in[4];
    const float* b1  = (const float*)d_in[5];
    const float* W2s = (const float*)d_in[6];
    const float* W2n = (const float*)d_in[7];
    const float* b2  = (const float*)d_in[8];
    const float* W3s = (const float*)d_in[9];
    const float* W3n = (const float*)d_in[10];
    const float* b3  = (const float*)d_in[11];
    const float* Wres = (const float*)d_in[12];
    const float* bres = (const float*)d_in[13];

    float* out_x   = (float*)d_out;
    float* out_res = out_x + (size_t)N_NODES * OUT_DIM;

    // ---- workspace layout ----
    size_t off = 0;
    auto carve = [&](size_t bytes) {
        size_t p = off;
        off += (bytes + 255) & ~(size_t)255;
        return p;
    };
    size_t o_cnt     = carve((size_t)N_NODES * 4);
    size_t o_rowptr  = carve((size_t)(N_NODES + 1) * 4);
    size_t o_cursor  = carve((size_t)N_NODES * 4);
    size_t o_invdeg  = carve((size_t)N_NODES * 4);
    size_t o_csr     = carve((size_t)N_EDGES * 4);
    size_t o_bsum    = carve((size_t)SCAN_NB * 4);
    size_t o_boff    = carve((size_t)SCAN_NB * 4);
    size_t o_w1   = carve((size_t)(H1 + OUT_DIM) * IN_DIM * 2);   // [W1s|Wres]T : 768 x 256
    size_t o_w1n  = carve((size_t)(H1 + OUT_DIM) * IN_DIM * 2);   // [W1n|0]T    : 768 x 256
    size_t o_w23  = carve((size_t)H1 * (H2 + H2) * 2);            // [W2n|W2s]T  : 640 x 640
    size_t o_w3   = carve((size_t)H2 * (OUT_DIM * 2) * 2);        // [W3n|W3s]T  : 256 x 320
    size_t o_regA = carve((size_t)N_NODES * (IN_DIM + IN_DIM) * 2);  // fX+aggF ; later x2
    size_t o_regB = carve((size_t)N_NODES * H1 * 2);                 // x1 ; later Y3+T3(f32)
    size_t o_regC = carve((size_t)N_NODES * H2 * 2);                 // Y2
    size_t o_regD = carve((size_t)N_NODES * H2 * 2);                 // T2
    size_t REQUIRED = off;
    if (ws_size < REQUIRED) return;

    char* W = (char*)d_ws;
    int*   cnt     = (int*)(W + o_cnt);
    int*   row_ptr = (int*)(W + o_rowptr);
    int*   cursor  = (int*)(W + o_cursor);
    float* inv_deg = (float*)(W + o_invdeg);
    int*   csr_src = (int*)(W + o_csr);
    int*   bsum    = (int*)(W + o_bsum);
    int*   boff    = (int*)(W + o_boff);
    u16* W1T  = (u16*)(W + o_w1);
    u16* W1nT = (u16*)(W + o_w1n);
    u16* W23T = (u16*)(W + o_w23);
    u16* W3T  = (u16*)(W + o_w3);
    u16* fX   = (u16*)(W + o_regA);
    u16* aggF = fX + (size_t)N_NODES * IN_DIM;
    u16* x2   = (u16*)(W + o_regA);                 // aliases fX+aggF (dead by then)
    u16* x1   = (u16*)(W + o_regB);
    u16* Y3   = (u16*)(W + o_regB);                 // aliases x1 (dead by then)
    float* T3 = (float*)(W + o_regB + (size_t)N_NODES * OUT_DIM * 2);
    u16* Y2   = (u16*)(W + o_regC);
    u16* T2   = (u16*)(W + o_regD);

    const int mt = (N_NODES + 127) / 128;

    // ---- CSR build (multi-block scan) ----
    zero2_kernel<<<(N_NODES + 255) / 256, 256, 0, stream>>>(cnt, cursor, N_NODES);
    count_deg_kernel<<<(N_EDGES + 255) / 256, 256, 0, stream>>>(edge_dst, cnt, N_EDGES);
    block_sum_kernel<<<SCAN_NB, SCAN_BLK, 0, stream>>>(cnt, bsum);
    scan_bsum_kernel<<<1, SCAN_BLK, 0, stream>>>(bsum, boff);
    final_scan_kernel<<<SCAN_NB, SCAN_BLK, 0, stream>>>(cnt, boff, row_ptr, inv_deg);
    scatter_kernel<<<(N_EDGES + 255) / 256, 256, 0, stream>>>(edge_src, edge_dst, row_ptr,
                                                              cursor, csr_src, N_EDGES);

    // ---- casts / transposes ----
    {
        int n4 = N_NODES * IN_DIM / 4;
        cast_kernel<<<(n4 + 255) / 256, 256, 0, stream>>>((const float4*)features,
                                                          (ushort4*)fX, n4);
    }
    {
        // zero the [W1n|0] pad rows (rows 640..767 of W1nT: 128*256 u16 = 8192 ints)
        int* pad = (int*)(W1nT + (size_t)H1 * IN_DIM);
        zero2_kernel<<<(8192 + 255) / 256, 256, 0, stream>>>(pad, pad, 8192);
        dim3 b(32, 8), g(20, 20, 7);
        transpose_all_kernel<<<g, b, 0, stream>>>(W1s, Wres, W1n, W2n, W2s, W3n, W3s,
                                                  W1T, W1nT, W23T, W3T);
    }

    // ---- layer 1 + residual (merged):
    //   [x1|res] = elu( fX@[W1s|Wres] + aggF@[W1n|0] + [b1|bres] ) ----
    aggregate_kernel<IN_DIM, 0><<<AGG_GRID, 256, 0, stream>>>(
        fX, row_ptr, csr_src, inv_deg, nullptr, nullptr, aggF);
    mfma_gemm_kernel<true, 4><<<((H1 + OUT_DIM) / 128) * mt, 256, 0, stream>>>(
        fX, aggF, W1T, W1nT, b1, bres, x1, out_res,
        N_NODES, IN_DIM, H1 + OUT_DIM, H1, (H1 + OUT_DIM) / 128);

    // ---- layer 2: [Y2|T2] = x1@[W2n|W2s]; x2 = elu(mean(Y2) + T2 + b2) ----
    mfma_gemm_kernel<false, 2><<<((H2 * 2) / 128) * mt, 256, 0, stream>>>(
        x1, nullptr, W23T, nullptr, nullptr, nullptr, Y2, T2,
        N_NODES, H1, H2 * 2, H2, (H2 * 2) / 128);
    aggregate_kernel<H2, 1><<<AGG_GRID, 256, 0, stream>>>(
        Y2, row_ptr, csr_src, inv_deg, T2, b2, x2);

    // ---- layer 3: [Y3|T3] = x2@[W3n|W3s]; out_x = elu(mean(Y3) + T3 + b3) ----
    mfma_gemm_kernel<false, 3><<<((OUT_DIM * 2) / 128) * mt, 256, 0, stream>>>(
        x2, nullptr, W3T, nullptr, nullptr, nullptr, Y3, T3,
        N_NODES, H2, OUT_DIM * 2, OUT_DIM, (OUT_DIM * 2) / 128);
    aggregate_kernel<OUT_DIM, 2><<<AGG_GRID, 256, 0, stream>>>(
        Y3, row_ptr, csr_src, inv_deg, T3, b3, out_x);
}

// Round 15
// 430.783 us; speedup vs baseline: 1.0791x; 1.0319x over previous
//
#include <hip/hip_runtime.h>
#include <hip/hip_bf16.h>
#include <cstdint>
#include <cstddef>

#define N_NODES 50000
#define N_EDGES 800000
#define IN_DIM 256
#define H1 640
#define H2 320
#define OUT_DIM 128

typedef unsigned short u16;
typedef __attribute__((ext_vector_type(8))) short short8v;   // 8 bf16 = 4 VGPR
typedef __attribute__((ext_vector_type(4))) float float4v;   // MFMA C/D

__device__ __forceinline__ float b2f(u16 u) {
    union { unsigned int i; float f; } v; v.i = ((unsigned int)u) << 16; return v.f;
}
__device__ __forceinline__ u16 f2b(float f) {
    __hip_bfloat16 h = __float2bfloat16(f);
    return *reinterpret_cast<u16*>(&h);
}

// ---------------------------------------------------------------------------
// CSR build (multi-block scan)
// ---------------------------------------------------------------------------

#define SCAN_BLK 256
#define SCAN_NB  ((N_NODES + SCAN_BLK - 1) / SCAN_BLK)   // 196

__global__ void zero2_kernel(int* __restrict__ a, int* __restrict__ b, int n) {
    int i = blockIdx.x * blockDim.x + threadIdx.x;
    if (i < n) { a[i] = 0; b[i] = 0; }
}

__global__ void count_deg_kernel(const int* __restrict__ dst, int* __restrict__ cnt, int nE) {
    int i = blockIdx.x * blockDim.x + threadIdx.x;
    if (i < nE) atomicAdd(&cnt[dst[i]], 1);
}

__global__ __launch_bounds__(SCAN_BLK)
void block_sum_kernel(const int* __restrict__ cnt, int* __restrict__ bsum) {
    __shared__ int red[SCAN_BLK];
    int t = threadIdx.x;
    int i = blockIdx.x * SCAN_BLK + t;
    red[t] = (i < N_NODES) ? cnt[i] : 0;
    __syncthreads();
#pragma unroll
    for (int off = SCAN_BLK / 2; off > 0; off >>= 1) {
        if (t < off) red[t] += red[t + off];
        __syncthreads();
    }
    if (t == 0) bsum[blockIdx.x] = red[0];
}

__global__ __launch_bounds__(SCAN_BLK)
void scan_bsum_kernel(const int* __restrict__ bsum, int* __restrict__ boff) {
    __shared__ int s[SCAN_BLK];
    int t = threadIdx.x;
    s[t] = (t < SCAN_NB) ? bsum[t] : 0;
    __syncthreads();
#pragma unroll
    for (int off = 1; off < SCAN_BLK; off <<= 1) {
        int v = (t >= off) ? s[t - off] : 0;
        __syncthreads();
        s[t] += v;
        __syncthreads();
    }
    if (t < SCAN_NB) boff[t] = (t == 0) ? 0 : s[t - 1];
}

__global__ __launch_bounds__(SCAN_BLK)
void final_scan_kernel(const int* __restrict__ cnt, const int* __restrict__ boff,
                       int* __restrict__ row_ptr, float* __restrict__ inv_deg) {
    __shared__ int s[SCAN_BLK];
    int b = blockIdx.x, t = threadIdx.x;
    int i = b * SCAN_BLK + t;
    int v = (i < N_NODES) ? cnt[i] : 0;
    s[t] = v;
    __syncthreads();
#pragma unroll
    for (int off = 1; off < SCAN_BLK; off <<= 1) {
        int u = (t >= off) ? s[t - off] : 0;
        __syncthreads();
        s[t] += u;
        __syncthreads();
    }
    if (i < N_NODES) {
        int base = boff[b];
        int incl = s[t];
        row_ptr[i] = base + incl - v;
        inv_deg[i] = (v > 0) ? (1.0f / (float)v) : 0.0f;
        if (i == N_NODES - 1) row_ptr[N_NODES] = base + incl;
    }
}

__global__ void scatter_kernel(const int* __restrict__ src, const int* __restrict__ dst,
                               const int* __restrict__ row_ptr, int* __restrict__ cursor,
                               int* __restrict__ csr_src, int nE) {
    int i = blockIdx.x * blockDim.x + threadIdx.x;
    if (i < nE) {
        int d = dst[i];
        int p = atomicAdd(&cursor[d], 1);
        csr_src[row_ptr[d] + p] = src[i];
    }
}

// ---------------------------------------------------------------------------
// f32 -> bf16 cast (vectorized)
// ---------------------------------------------------------------------------

__global__ void cast_kernel(const float4* __restrict__ in, ushort4* __restrict__ out, int n4) {
    int i = blockIdx.x * blockDim.x + threadIdx.x;
    if (i < n4) {
        float4 v = in[i];
        ushort4 o;
        o.x = f2b(v.x); o.y = f2b(v.y); o.z = f2b(v.z); o.w = f2b(v.w);
        out[i] = o;
    }
}

// ---------------------------------------------------------------------------
// Batched weight transpose+cast: all 7 weights in one launch (blockIdx.z).
// in f32 [K][N] -> out bf16 [rowOff + N][K]
// ---------------------------------------------------------------------------

__global__ __launch_bounds__(256)
void transpose_all_kernel(const float* __restrict__ W1s, const float* __restrict__ Wres,
                          const float* __restrict__ W1n, const float* __restrict__ W2n,
                          const float* __restrict__ W2s, const float* __restrict__ W3n,
                          const float* __restrict__ W3s,
                          u16* __restrict__ W1T, u16* __restrict__ W1nT,
                          u16* __restrict__ W23T, u16* __restrict__ W3T) {
    const float* in; u16* out; int K, N, rowOff;
    switch (blockIdx.z) {
        case 0: in = W1s;  out = W1T;  K = 256; N = 640; rowOff = 0;   break;
        case 1: in = Wres; out = W1T;  K = 256; N = 128; rowOff = 640; break;
        case 2: in = W1n;  out = W1nT; K = 256; N = 640; rowOff = 0;   break;
        case 3: in = W2n;  out = W23T; K = 640; N = 320; rowOff = 0;   break;
        case 4: in = W2s;  out = W23T; K = 640; N = 320; rowOff = 320; break;
        case 5: in = W3n;  out = W3T;  K = 320; N = 128; rowOff = 0;   break;
        default: in = W3s; out = W3T;  K = 320; N = 128; rowOff = 128; break;
    }
    int bx = blockIdx.x * 32;   // N direction
    int by = blockIdx.y * 32;   // K direction
    if (bx >= N || by >= K) return;
    __shared__ float t[32][33];
    int x = threadIdx.x;        // 0..31
    int y = threadIdx.y;        // 0..7
#pragma unroll
    for (int i = 0; i < 32; i += 8) {
        int r = by + y + i, c = bx + x;
        if (r < K && c < N) t[y + i][x] = in[(size_t)r * N + c];
    }
    __syncthreads();
#pragma unroll
    for (int i = 0; i < 32; i += 8) {
        int r = bx + y + i, c = by + x;
        if (r < N && c < K) out[(size_t)(rowOff + r) * K + c] = f2b(t[x][y + i]);
    }
}

// ---------------------------------------------------------------------------
// Mean aggregation — block-level lane groups, no LDS, no barriers.
// group g = t/L owns one node (L = D/8 lanes, each a 16B col-slice);
// Edge loop unrolled x4 (4 independent gathers in flight per lane).
// Persistent grid-stride.
// MODE 0: out_bf16 = sum * w
// MODE 1: out_bf16 = elu(sum*w + T_bf16 + bias)
// MODE 2: out_f32  = elu(sum*w + T_f32  + bias)
// ---------------------------------------------------------------------------

#define AGG_GRID 2048

template<int D, int MODE>
__global__ __launch_bounds__(256, 8)
void aggregate_kernel(const u16* __restrict__ h, const int* __restrict__ row_ptr,
                      const int* __restrict__ csr_src, const float* __restrict__ inv_deg,
                      const void* __restrict__ T, const float* __restrict__ bias,
                      void* __restrict__ out) {
    constexpr int L = D / 8;             // lanes per group
    constexpr int GPB = 256 / L;         // groups per block (D=320: 6, 240 thr)
    int t = threadIdx.x;
    int g = t / L, cl = t % L;
    if (g >= GPB) return;                // only trims threads for D=320

    float bv[8];
    if (MODE != 0) {
        const float* bp = bias + cl * 8;
        float4 ba = *(const float4*)bp, bb = *(const float4*)(bp + 4);
        bv[0] = ba.x; bv[1] = ba.y; bv[2] = ba.z; bv[3] = ba.w;
        bv[4] = bb.x; bv[5] = bb.y; bv[6] = bb.z; bv[7] = bb.w;
    }

    const u16* __restrict__ hb = h + cl * 8;
    const int stride = gridDim.x * GPB;
    for (int node = blockIdx.x * GPB + g; node < N_NODES; node += stride) {
        int e0 = row_ptr[node], e1 = row_ptr[node + 1];
        float acc[8];
#pragma unroll
        for (int j = 0; j < 8; ++j) acc[j] = 0.0f;

        for (int e = e0; e < e1; e += 4) {
            int idx[4]; float msk[4];
#pragma unroll
            for (int u = 0; u < 4; ++u) {
                int ee = e + u;
                msk[u] = (ee < e1) ? 1.0f : 0.0f;
                idx[u] = csr_src[(ee < e1) ? ee : e];
            }
            short8v v[4];
#pragma unroll
            for (int u = 0; u < 4; ++u)
                v[u] = *(const short8v*)(hb + (size_t)idx[u] * D);
#pragma unroll
            for (int u = 0; u < 4; ++u)
#pragma unroll
                for (int j = 0; j < 8; ++j)
                    acc[j] += msk[u] * b2f((u16)v[u][j]);
        }

        float w = inv_deg[node];
        if (MODE == 0) {
            short8v o;
#pragma unroll
            for (int j = 0; j < 8; ++j) o[j] = (short)f2b(acc[j] * w);
            *(short8v*)((u16*)out + (size_t)node * D + cl * 8) = o;
        } else if (MODE == 1) {
            short8v tb = *(const short8v*)((const u16*)T + (size_t)node * D + cl * 8);
            short8v o;
#pragma unroll
            for (int j = 0; j < 8; ++j) {
                float x = acc[j] * w + b2f((u16)tb[j]) + bv[j];
                x = (x > 0.0f) ? x : expm1f(x);
                o[j] = (short)f2b(x);
            }
            *(short8v*)((u16*)out + (size_t)node * D + cl * 8) = o;
        } else {
            const float* tp = (const float*)T + (size_t)node * D + cl * 8;
            float4 ta = *(const float4*)tp, tb4 = *(const float4*)(tp + 4);
            float tv[8] = {ta.x, ta.y, ta.z, ta.w, tb4.x, tb4.y, tb4.z, tb4.w};
            float v8[8];
#pragma unroll
            for (int j = 0; j < 8; ++j) {
                float x = acc[j] * w + tv[j] + bv[j];
                v8[j] = (x > 0.0f) ? x : expm1f(x);
            }
            float* op = (float*)out + (size_t)node * D + cl * 8;
            *(float4*)op = make_float4(v8[0], v8[1], v8[2], v8[3]);
            *(float4*)(op + 4) = make_float4(v8[4], v8[5], v8[6], v8[7]);
        }
    }
}

// ---------------------------------------------------------------------------
// MFMA GEMM — r15: BM=256 x BN=128, 512 threads (8 waves, 4Mx2N), 3-buffer
// ring / 72 KB LDS, counted vmcnt. Same per-wave 64x64 tile and schedule as
// r12/r14; the change is occupancy shape: 2 blocks x 8 waves = 16 waves/CU
// (vs 3x4=12) and half the grid (tail rounds fuller: L2 980/512=1.91 vs
// 1955/768=2.55). Loads/thread/step = 3 (2 A-chunks + 1 B-chunk) -> steady
// wait vmcnt(3) (one future buffer in flight), vmcnt(0) only on last step.
// Hazards: RAW = own counted vmcnt + barrier; WAR = buffer (kt+2)%3 written
// after the step-kt barrier was last read at step kt-1 (all waves past it).
// 2-way-free swizzle cg/sw = x ^ ((row>>1)&3) both sides. W bf16 [N][K].
// EPI 0: C0 bf16 = elu(acc + bias)
// EPI 2: split at N0: C0 bf16 raw | C1 bf16 raw
// EPI 3: split at N0: C0 bf16 raw | C1 f32 raw
// EPI 4: split at N0: C0 bf16 elu(+bias) | C1 f32 elu(+bias2)
// Grid 1D with bijective XCD swizzle; N % 128 == 0, K % 32 == 0, M ragged.
// ---------------------------------------------------------------------------

template<bool DUAL, int EPI>
__global__ __launch_bounds__(512)
void mfma_gemm_kernel(const u16* __restrict__ A0, const u16* __restrict__ A1,
                      const u16* __restrict__ W0T, const u16* __restrict__ W1T,
                      const float* __restrict__ bias, const float* __restrict__ bias2,
                      void* __restrict__ C0, void* __restrict__ C1,
                      int M, int K, int N, int N0, int gx) {
    // bijective XCD swizzle (m204)
    int nwg = gridDim.x;
    int d = blockIdx.x;
    int q = nwg >> 3, r8 = nwg & 7;
    int xcd = d & 7, idx = d >> 3;
    int flat = (xcd < r8 ? xcd * (q + 1) : r8 * (q + 1) + (xcd - r8) * q) + idx;
    int bxt = flat % gx, byt = flat / gx;

    int tid = threadIdx.x;
    int wid = tid >> 6;        // 0..7
    int lane = tid & 63;
    int lr = lane & 15;        // row (A) / col (B) within fragment
    int lb = lane >> 4;        // k-chunk 0..3 (8 elems = 16 B each)
    int wr = wid >> 1;         // wave row 0..3 (M dir)
    int wc = wid & 1;          // wave col 0..1 (N dir)

    int bm = byt * 256;        // block row base
    int bn = bxt * 128;        // block col base

    // LDS: 3 buffers x [A 8192 u16 (256x32) | B 4096 u16 (128x32)] = 72 KB
    __shared__ u16 smem[3 * 12288];

    const int NT0 = K >> 5;                    // K-steps per stream
    const int NT = DUAL ? (NT0 * 2) : NT0;

    // ---- hoisted staging state (per thread: 2 A-chunks + 1 B-chunk) ----
    int c  = tid & 3;                          // 16B chunk-in-row
    int rr = tid >> 2;                         // staging row 0..127
    int cg = c ^ ((rr >> 1) & 3);              // 2-way-free source swizzle
                                               // (rows rr and rr+128 share cg: 128>>1=64 ≡ 0 mod 4)
    int rA0 = bm + rr;       if (rA0 > M - 1) rA0 = M - 1;
    int rA1 = bm + rr + 128; if (rA1 > M - 1) rA1 = M - 1;
    const u16* pA0 = A0 + (size_t)rA0 * K + cg * 8;
    const u16* pA1 = A0 + (size_t)rA1 * K + cg * 8;
    const u16* pB0 = W0T + (size_t)(bn + rr) * K + cg * 8;  // rr<128, bn+127<N
    int dA0 = tid * 8, dA1 = (tid + 512) * 8;  // A chunk LDS offsets (u16)
    int dB0 = 8192 + tid * 8;                  // B region starts at 8192 u16

    auto issue = [&](int buf) {
        u16* ab = smem + buf * 12288;
        __builtin_amdgcn_global_load_lds(
            (const __attribute__((address_space(1))) void*)pA0,
            (__attribute__((address_space(3))) void*)(ab + dA0), 16, 0, 0);
        __builtin_amdgcn_global_load_lds(
            (const __attribute__((address_space(1))) void*)pA1,
            (__attribute__((address_space(3))) void*)(ab + dA1), 16, 0, 0);
        __builtin_amdgcn_global_load_lds(
            (const __attribute__((address_space(1))) void*)pB0,
            (__attribute__((address_space(3))) void*)(ab + dB0), 16, 0, 0);
        pA0 += 32; pA1 += 32; pB0 += 32;
    };

    float4v acc[4][4] = {};

    // prologue: stage K-steps 0 and 1 into buffers 0 and 1 (NT >= 8 here)
    issue(0);
    issue(1);

    int sw = lb ^ ((lr >> 1) & 3);             // 2-way-free read swizzle
    int rdA = (wr * 64 + lr) * 32 + sw * 8;    // + i*512 per fragment (16 rows)
    int rdB = 8192 + (wc * 64 + lr) * 32 + sw * 8;

    for (int kt = 0; kt < NT; ++kt) {
        // counted vmcnt: wait only for the buffer we're about to read.
        if (kt + 1 < NT) asm volatile("s_waitcnt vmcnt(3)" ::: "memory");
        else             asm volatile("s_waitcnt vmcnt(0)" ::: "memory");
        __builtin_amdgcn_s_barrier();          // all waves' loads for this buf landed

        const u16* base = smem + (kt % 3) * 12288;
        short8v af[4], bf[4];
#pragma unroll
        for (int i = 0; i < 4; ++i)
            af[i] = *(const short8v*)(base + rdA + i * 512);
#pragma unroll
        for (int j = 0; j < 4; ++j)
            bf[j] = *(const short8v*)(base + rdB + j * 512);

        // stage K-step kt+2 into the buffer last read at iter kt-1
        if (kt + 2 < NT) {
            if (DUAL && kt + 2 == NT0) {       // stream seam: reset pointers
                pA0 = A1 + (size_t)rA0 * K + cg * 8;
                pA1 = A1 + (size_t)rA1 * K + cg * 8;
                pB0 = W1T + (size_t)(bn + rr) * K + cg * 8;
            }
            issue((kt + 2) % 3);
        }

        __builtin_amdgcn_s_setprio(1);
#pragma unroll
        for (int i = 0; i < 4; ++i)
#pragma unroll
            for (int j = 0; j < 4; ++j)
                acc[i][j] = __builtin_amdgcn_mfma_f32_16x16x32_bf16(
                    af[i], bf[j], acc[i][j], 0, 0, 0);
        __builtin_amdgcn_s_setprio(0);
    }

    // epilogue: C[bm + wr*64 + i*16 + lb*4 + rr2][bn + wc*64 + j*16 + lr]
    int bmw = bm + wr * 64, bnw = bn + wc * 64;
    if (EPI == 0) {
        float bi[4];
#pragma unroll
        for (int j = 0; j < 4; ++j) bi[j] = bias[bnw + j * 16 + lr];
#pragma unroll
        for (int i = 0; i < 4; ++i) {
#pragma unroll
            for (int rr2 = 0; rr2 < 4; ++rr2) {
                int row = bmw + i * 16 + lb * 4 + rr2;
                if (row >= M) continue;
#pragma unroll
                for (int j = 0; j < 4; ++j) {
                    int col = bnw + j * 16 + lr;
                    float v = acc[i][j][rr2] + bi[j];
                    v = (v > 0.0f) ? v : expm1f(v);
                    ((u16*)C0)[(size_t)row * N + col] = f2b(v);
                }
            }
        }
    } else if (EPI == 4) {
        // tiles never straddle N0 (N0 % 128 == 0)
        bool resTile = (bnw >= N0);
        int N1 = N - N0;
        float bi[4];
#pragma unroll
        for (int j = 0; j < 4; ++j) {
            int cidx = bnw + j * 16 + lr;
            bi[j] = resTile ? bias2[cidx - N0] : bias[cidx];
        }
#pragma unroll
        for (int i = 0; i < 4; ++i) {
#pragma unroll
            for (int rr2 = 0; rr2 < 4; ++rr2) {
                int row = bmw + i * 16 + lb * 4 + rr2;
                if (row >= M) continue;
#pragma unroll
                for (int j = 0; j < 4; ++j) {
                    int col = bnw + j * 16 + lr;
                    float v = acc[i][j][rr2] + bi[j];
                    v = (v > 0.0f) ? v : expm1f(v);
                    if (resTile) ((float*)C1)[(size_t)row * N1 + (col - N0)] = v;
                    else         ((u16*)C0)[(size_t)row * N0 + col] = f2b(v);
                }
            }
        }
    } else {
        int N1 = N - N0;
#pragma unroll
        for (int i = 0; i < 4; ++i) {
#pragma unroll
            for (int rr2 = 0; rr2 < 4; ++rr2) {
                int row = bmw + i * 16 + lb * 4 + rr2;
                if (row >= M) continue;
#pragma unroll
                for (int j = 0; j < 4; ++j) {
                    int col = bnw + j * 16 + lr;
                    float v = acc[i][j][rr2];
                    if (col < N0) {
                        ((u16*)C0)[(size_t)row * N0 + col] = f2b(v);
                    } else {
                        int c1 = col - N0;
                        if (EPI == 3) ((float*)C1)[(size_t)row * N1 + c1] = v;
                        else          ((u16*)C1)[(size_t)row * N1 + c1] = f2b(v);
                    }
                }
            }
        }
    }
}

// ---------------------------------------------------------------------------

extern "C" void kernel_launch(void* const* d_in, const int* in_sizes, int n_in,
                              void* d_out, int out_size, void* d_ws, size_t ws_size,
                              hipStream_t stream) {
    const float* features = (const float*)d_in[0];
    const int*   edge_src = (const int*)d_in[1];
    const int*   edge_dst = (const int*)d_in[2];
    const float* W1s = (const float*)d_in[3];
    const float* W1n = (const float*)d_in[4];
    const float* b1  = (const float*)d_in[5];
    const float* W2s = (const float*)d_in[6];
    const float* W2n = (const float*)d_in[7];
    const float* b2  = (const float*)d_in[8];
    const float* W3s = (const float*)d_in[9];
    const float* W3n = (const float*)d_in[10];
    const float* b3  = (const float*)d_in[11];
    const float* Wres = (const float*)d_in[12];
    const float* bres = (const float*)d_in[13];

    float* out_x   = (float*)d_out;
    float* out_res = out_x + (size_t)N_NODES * OUT_DIM;

    // ---- workspace layout ----
    size_t off = 0;
    auto carve = [&](size_t bytes) {
        size_t p = off;
        off += (bytes + 255) & ~(size_t)255;
        return p;
    };
    size_t o_cnt     = carve((size_t)N_NODES * 4);
    size_t o_rowptr  = carve((size_t)(N_NODES + 1) * 4);
    size_t o_cursor  = carve((size_t)N_NODES * 4);
    size_t o_invdeg  = carve((size_t)N_NODES * 4);
    size_t o_csr     = carve((size_t)N_EDGES * 4);
    size_t o_bsum    = carve((size_t)SCAN_NB * 4);
    size_t o_boff    = carve((size_t)SCAN_NB * 4);
    size_t o_w1   = carve((size_t)(H1 + OUT_DIM) * IN_DIM * 2);   // [W1s|Wres]T : 768 x 256
    size_t o_w1n  = carve((size_t)(H1 + OUT_DIM) * IN_DIM * 2);   // [W1n|0]T    : 768 x 256
    size_t o_w23  = carve((size_t)H1 * (H2 + H2) * 2);            // [W2n|W2s]T  : 640 x 640
    size_t o_w3   = carve((size_t)H2 * (OUT_DIM * 2) * 2);        // [W3n|W3s]T  : 256 x 320
    size_t o_regA = carve((size_t)N_NODES * (IN_DIM + IN_DIM) * 2);  // fX+aggF ; later x2
    size_t o_regB = carve((size_t)N_NODES * H1 * 2);                 // x1 ; later Y3+T3(f32)
    size_t o_regC = carve((size_t)N_NODES * H2 * 2);                 // Y2
    size_t o_regD = carve((size_t)N_NODES * H2 * 2);                 // T2
    size_t REQUIRED = off;
    if (ws_size < REQUIRED) return;

    char* W = (char*)d_ws;
    int*   cnt     = (int*)(W + o_cnt);
    int*   row_ptr = (int*)(W + o_rowptr);
    int*   cursor  = (int*)(W + o_cursor);
    float* inv_deg = (float*)(W + o_invdeg);
    int*   csr_src = (int*)(W + o_csr);
    int*   bsum    = (int*)(W + o_bsum);
    int*   boff    = (int*)(W + o_boff);
    u16* W1T  = (u16*)(W + o_w1);
    u16* W1nT = (u16*)(W + o_w1n);
    u16* W23T = (u16*)(W + o_w23);
    u16* W3T  = (u16*)(W + o_w3);
    u16* fX   = (u16*)(W + o_regA);
    u16* aggF = fX + (size_t)N_NODES * IN_DIM;
    u16* x2   = (u16*)(W + o_regA);                 // aliases fX+aggF (dead by then)
    u16* x1   = (u16*)(W + o_regB);
    u16* Y3   = (u16*)(W + o_regB);                 // aliases x1 (dead by then)
    float* T3 = (float*)(W + o_regB + (size_t)N_NODES * OUT_DIM * 2);
    u16* Y2   = (u16*)(W + o_regC);
    u16* T2   = (u16*)(W + o_regD);

    const int mt = (N_NODES + 255) / 256;   // 196 M-tiles of 256

    // ---- CSR build (multi-block scan) ----
    zero2_kernel<<<(N_NODES + 255) / 256, 256, 0, stream>>>(cnt, cursor, N_NODES);
    count_deg_kernel<<<(N_EDGES + 255) / 256, 256, 0, stream>>>(edge_dst, cnt, N_EDGES);
    block_sum_kernel<<<SCAN_NB, SCAN_BLK, 0, stream>>>(cnt, bsum);
    scan_bsum_kernel<<<1, SCAN_BLK, 0, stream>>>(bsum, boff);
    final_scan_kernel<<<SCAN_NB, SCAN_BLK, 0, stream>>>(cnt, boff, row_ptr, inv_deg);
    scatter_kernel<<<(N_EDGES + 255) / 256, 256, 0, stream>>>(edge_src, edge_dst, row_ptr,
                                                              cursor, csr_src, N_EDGES);

    // ---- casts / transposes ----
    {
        int n4 = N_NODES * IN_DIM / 4;
        cast_kernel<<<(n4 + 255) / 256, 256, 0, stream>>>((const float4*)features,
                                                          (ushort4*)fX, n4);
    }
    {
        // zero the [W1n|0] pad rows (rows 640..767 of W1nT: 128*256 u16 = 8192 ints)
        int* pad = (int*)(W1nT + (size_t)H1 * IN_DIM);
        zero2_kernel<<<(8192 + 255) / 256, 256, 0, stream>>>(pad, pad, 8192);
        dim3 b(32, 8), g(20, 20, 7);
        transpose_all_kernel<<<g, b, 0, stream>>>(W1s, Wres, W1n, W2n, W2s, W3n, W3s,
                                                  W1T, W1nT, W23T, W3T);
    }

    // ---- layer 1 + residual (merged):
    //   [x1|res] = elu( fX@[W1s|Wres] + aggF@[W1n|0] + [b1|bres] ) ----
    aggregate_kernel<IN_DIM, 0><<<AGG_GRID, 256, 0, stream>>>(
        fX, row_ptr, csr_src, inv_deg, nullptr, nullptr, aggF);
    mfma_gemm_kernel<true, 4><<<((H1 + OUT_DIM) / 128) * mt, 512, 0, stream>>>(
        fX, aggF, W1T, W1nT, b1, bres, x1, out_res,
        N_NODES, IN_DIM, H1 + OUT_DIM, H1, (H1 + OUT_DIM) / 128);

    // ---- layer 2: [Y2|T2] = x1@[W2n|W2s]; x2 = elu(mean(Y2) + T2 + b2) ----
    mfma_gemm_kernel<false, 2><<<((H2 * 2) / 128) * mt, 512, 0, stream>>>(
        x1, nullptr, W23T, nullptr, nullptr, nullptr, Y2, T2,
        N_NODES, H1, H2 * 2, H2, (H2 * 2) / 128);
    aggregate_kernel<H2, 1><<<AGG_GRID, 256, 0, stream>>>(
        Y2, row_ptr, csr_src, inv_deg, T2, b2, x2);

    // ---- layer 3: [Y3|T3] = x2@[W3n|W3s]; out_x = elu(mean(Y3) + T3 + b3) ----
    mfma_gemm_kernel<false, 3><<<((OUT_DIM * 2) / 128) * mt, 512, 0, stream>>>(
        x2, nullptr, W3T, nullptr, nullptr, nullptr, Y3, T3,
        N_NODES, H2, OUT_DIM * 2, OUT_DIM, (OUT_DIM * 2) / 128);
    aggregate_kernel<OUT_DIM, 2><<<AGG_GRID, 256, 0, stream>>>(
        Y3, row_ptr, csr_src, inv_deg, T3, b3, out_x);
}

// Round 16
// 427.343 us; speedup vs baseline: 1.0878x; 1.0080x over previous
//
#include <hip/hip_runtime.h>
#include <hip/hip_bf16.h>
#include <cstdint>
#include <cstddef>

#define N_NODES 50000
#define N_EDGES 800000
#define IN_DIM 256
#define H1 640
#define H2 320
#define OUT_DIM 128

typedef unsigned short u16;
typedef __attribute__((ext_vector_type(8))) short short8v;   // 8 bf16 = 4 VGPR
typedef __attribute__((ext_vector_type(4))) float float4v;   // MFMA C/D

__device__ __forceinline__ float b2f(u16 u) {
    union { unsigned int i; float f; } v; v.i = ((unsigned int)u) << 16; return v.f;
}
__device__ __forceinline__ u16 f2b(float f) {
    __hip_bfloat16 h = __float2bfloat16(f);
    return *reinterpret_cast<u16*>(&h);
}

// ---------------------------------------------------------------------------
// CSR build (multi-block scan)
// ---------------------------------------------------------------------------

#define SCAN_BLK 256
#define SCAN_NB  ((N_NODES + SCAN_BLK - 1) / SCAN_BLK)   // 196

__global__ void zero2_kernel(int* __restrict__ a, int* __restrict__ b, int n) {
    int i = blockIdx.x * blockDim.x + threadIdx.x;
    if (i < n) { a[i] = 0; b[i] = 0; }
}

__global__ void count_deg_kernel(const int* __restrict__ dst, int* __restrict__ cnt, int nE) {
    int i = blockIdx.x * blockDim.x + threadIdx.x;
    if (i < nE) atomicAdd(&cnt[dst[i]], 1);
}

__global__ __launch_bounds__(SCAN_BLK)
void block_sum_kernel(const int* __restrict__ cnt, int* __restrict__ bsum) {
    __shared__ int red[SCAN_BLK];
    int t = threadIdx.x;
    int i = blockIdx.x * SCAN_BLK + t;
    red[t] = (i < N_NODES) ? cnt[i] : 0;
    __syncthreads();
#pragma unroll
    for (int off = SCAN_BLK / 2; off > 0; off >>= 1) {
        if (t < off) red[t] += red[t + off];
        __syncthreads();
    }
    if (t == 0) bsum[blockIdx.x] = red[0];
}

__global__ __launch_bounds__(SCAN_BLK)
void scan_bsum_kernel(const int* __restrict__ bsum, int* __restrict__ boff) {
    __shared__ int s[SCAN_BLK];
    int t = threadIdx.x;
    s[t] = (t < SCAN_NB) ? bsum[t] : 0;
    __syncthreads();
#pragma unroll
    for (int off = 1; off < SCAN_BLK; off <<= 1) {
        int v = (t >= off) ? s[t - off] : 0;
        __syncthreads();
        s[t] += v;
        __syncthreads();
    }
    if (t < SCAN_NB) boff[t] = (t == 0) ? 0 : s[t - 1];
}

__global__ __launch_bounds__(SCAN_BLK)
void final_scan_kernel(const int* __restrict__ cnt, const int* __restrict__ boff,
                       int* __restrict__ row_ptr, float* __restrict__ inv_deg) {
    __shared__ int s[SCAN_BLK];
    int b = blockIdx.x, t = threadIdx.x;
    int i = b * SCAN_BLK + t;
    int v = (i < N_NODES) ? cnt[i] : 0;
    s[t] = v;
    __syncthreads();
#pragma unroll
    for (int off = 1; off < SCAN_BLK; off <<= 1) {
        int u = (t >= off) ? s[t - off] : 0;
        __syncthreads();
        s[t] += u;
        __syncthreads();
    }
    if (i < N_NODES) {
        int base = boff[b];
        int incl = s[t];
        row_ptr[i] = base + incl - v;
        inv_deg[i] = (v > 0) ? (1.0f / (float)v) : 0.0f;
        if (i == N_NODES - 1) row_ptr[N_NODES] = base + incl;
    }
}

__global__ void scatter_kernel(const int* __restrict__ src, const int* __restrict__ dst,
                               const int* __restrict__ row_ptr, int* __restrict__ cursor,
                               int* __restrict__ csr_src, int nE) {
    int i = blockIdx.x * blockDim.x + threadIdx.x;
    if (i < nE) {
        int d = dst[i];
        int p = atomicAdd(&cursor[d], 1);
        csr_src[row_ptr[d] + p] = src[i];
    }
}

// ---------------------------------------------------------------------------
// f32 -> bf16 cast (vectorized)
// ---------------------------------------------------------------------------

__global__ void cast_kernel(const float4* __restrict__ in, ushort4* __restrict__ out, int n4) {
    int i = blockIdx.x * blockDim.x + threadIdx.x;
    if (i < n4) {
        float4 v = in[i];
        ushort4 o;
        o.x = f2b(v.x); o.y = f2b(v.y); o.z = f2b(v.z); o.w = f2b(v.w);
        out[i] = o;
    }
}

// ---------------------------------------------------------------------------
// Batched weight transpose+cast: all 7 weights in one launch (blockIdx.z).
// in f32 [K][N] -> out bf16 [rowOff + N][K]
// ---------------------------------------------------------------------------

__global__ __launch_bounds__(256)
void transpose_all_kernel(const float* __restrict__ W1s, const float* __restrict__ Wres,
                          const float* __restrict__ W1n, const float* __restrict__ W2n,
                          const float* __restrict__ W2s, const float* __restrict__ W3n,
                          const float* __restrict__ W3s,
                          u16* __restrict__ W1T, u16* __restrict__ W1nT,
                          u16* __restrict__ W23T, u16* __restrict__ W3T) {
    const float* in; u16* out; int K, N, rowOff;
    switch (blockIdx.z) {
        case 0: in = W1s;  out = W1T;  K = 256; N = 640; rowOff = 0;   break;
        case 1: in = Wres; out = W1T;  K = 256; N = 128; rowOff = 640; break;
        case 2: in = W1n;  out = W1nT; K = 256; N = 640; rowOff = 0;   break;
        case 3: in = W2n;  out = W23T; K = 640; N = 320; rowOff = 0;   break;
        case 4: in = W2s;  out = W23T; K = 640; N = 320; rowOff = 320; break;
        case 5: in = W3n;  out = W3T;  K = 320; N = 128; rowOff = 0;   break;
        default: in = W3s; out = W3T;  K = 320; N = 128; rowOff = 128; break;
    }
    int bx = blockIdx.x * 32;   // N direction
    int by = blockIdx.y * 32;   // K direction
    if (bx >= N || by >= K) return;
    __shared__ float t[32][33];
    int x = threadIdx.x;        // 0..31
    int y = threadIdx.y;        // 0..7
#pragma unroll
    for (int i = 0; i < 32; i += 8) {
        int r = by + y + i, c = bx + x;
        if (r < K && c < N) t[y + i][x] = in[(size_t)r * N + c];
    }
    __syncthreads();
#pragma unroll
    for (int i = 0; i < 32; i += 8) {
        int r = bx + y + i, c = by + x;
        if (r < N && c < K) out[(size_t)(rowOff + r) * K + c] = f2b(t[x][y + i]);
    }
}

// ---------------------------------------------------------------------------
// Mean aggregation — block-level lane groups, no LDS, no barriers.
// group g = t/L owns one node (L = D/8 lanes, each a 16B col-slice).
// r16: edge loop split into UNMASKED main 4-chunks + <=3-edge scalar tail
// (r9 counters: VALUBusy 59% — the per-chunk msk cmp/cndmask/idx-select was
// ~25% of loop VALU and only needed on the last chunk). Bit-identical
// summation order (masked zero-adds removed, edge order unchanged).
// Persistent grid-stride.
// MODE 0: out_bf16 = sum * w
// MODE 1: out_bf16 = elu(sum*w + T_bf16 + bias)
// MODE 2: out_f32  = elu(sum*w + T_f32  + bias)
// ---------------------------------------------------------------------------

#define AGG_GRID 2048

template<int D, int MODE>
__global__ __launch_bounds__(256, 8)
void aggregate_kernel(const u16* __restrict__ h, const int* __restrict__ row_ptr,
                      const int* __restrict__ csr_src, const float* __restrict__ inv_deg,
                      const void* __restrict__ T, const float* __restrict__ bias,
                      void* __restrict__ out) {
    constexpr int L = D / 8;             // lanes per group
    constexpr int GPB = 256 / L;         // groups per block (D=320: 6, 240 thr)
    int t = threadIdx.x;
    int g = t / L, cl = t % L;
    if (g >= GPB) return;                // only trims threads for D=320

    float bv[8];
    if (MODE != 0) {
        const float* bp = bias + cl * 8;
        float4 ba = *(const float4*)bp, bb = *(const float4*)(bp + 4);
        bv[0] = ba.x; bv[1] = ba.y; bv[2] = ba.z; bv[3] = ba.w;
        bv[4] = bb.x; bv[5] = bb.y; bv[6] = bb.z; bv[7] = bb.w;
    }

    const u16* __restrict__ hb = h + cl * 8;
    const int stride = gridDim.x * GPB;
    for (int node = blockIdx.x * GPB + g; node < N_NODES; node += stride) {
        int e0 = row_ptr[node], e1 = row_ptr[node + 1];
        float acc[8];
#pragma unroll
        for (int j = 0; j < 8; ++j) acc[j] = 0.0f;

        int e = e0;
        int eMain = e0 + ((e1 - e0) & ~3);       // full 4-chunks

        for (; e < eMain; e += 4) {              // unmasked main loop
            int idx[4];
#pragma unroll
            for (int u = 0; u < 4; ++u) idx[u] = csr_src[e + u];
            short8v v[4];
#pragma unroll
            for (int u = 0; u < 4; ++u)
                v[u] = *(const short8v*)(hb + (size_t)idx[u] * D);
#pragma unroll
            for (int u = 0; u < 4; ++u)
#pragma unroll
                for (int j = 0; j < 8; ++j)
                    acc[j] += b2f((u16)v[u][j]);
        }
        for (; e < e1; ++e) {                    // <=3-edge tail
            int s = csr_src[e];
            short8v v = *(const short8v*)(hb + (size_t)s * D);
#pragma unroll
            for (int j = 0; j < 8; ++j) acc[j] += b2f((u16)v[j]);
        }

        float w = inv_deg[node];
        if (MODE == 0) {
            short8v o;
#pragma unroll
            for (int j = 0; j < 8; ++j) o[j] = (short)f2b(acc[j] * w);
            *(short8v*)((u16*)out + (size_t)node * D + cl * 8) = o;
        } else if (MODE == 1) {
            short8v tb = *(const short8v*)((const u16*)T + (size_t)node * D + cl * 8);
            short8v o;
#pragma unroll
            for (int j = 0; j < 8; ++j) {
                float x = acc[j] * w + b2f((u16)tb[j]) + bv[j];
                x = (x > 0.0f) ? x : expm1f(x);
                o[j] = (short)f2b(x);
            }
            *(short8v*)((u16*)out + (size_t)node * D + cl * 8) = o;
        } else {
            const float* tp = (const float*)T + (size_t)node * D + cl * 8;
            float4 ta = *(const float4*)tp, tb4 = *(const float4*)(tp + 4);
            float tv[8] = {ta.x, ta.y, ta.z, ta.w, tb4.x, tb4.y, tb4.z, tb4.w};
            float v8[8];
#pragma unroll
            for (int j = 0; j < 8; ++j) {
                float x = acc[j] * w + tv[j] + bv[j];
                v8[j] = (x > 0.0f) ? x : expm1f(x);
            }
            float* op = (float*)out + (size_t)node * D + cl * 8;
            *(float4*)op = make_float4(v8[0], v8[1], v8[2], v8[3]);
            *(float4*)(op + 4) = make_float4(v8[4], v8[5], v8[6], v8[7]);
        }
    }
}

// ---------------------------------------------------------------------------
// MFMA GEMM — r15 structure (frozen): BM=256 x BN=128, 512 threads (8 waves,
// 4Mx2N), 3-buffer ring / 72 KB LDS, counted vmcnt (steady vmcnt(3), final
// vmcnt(0)), 2-way-free swizzle, bijective XCD swizzle. W bf16 [N][K].
// EPI 0: C0 bf16 = elu(acc + bias)
// EPI 2: split at N0: C0 bf16 raw | C1 bf16 raw
// EPI 3: split at N0: C0 bf16 raw | C1 f32 raw
// EPI 4: split at N0: C0 bf16 elu(+bias) | C1 f32 elu(+bias2)
// ---------------------------------------------------------------------------

template<bool DUAL, int EPI>
__global__ __launch_bounds__(512)
void mfma_gemm_kernel(const u16* __restrict__ A0, const u16* __restrict__ A1,
                      const u16* __restrict__ W0T, const u16* __restrict__ W1T,
                      const float* __restrict__ bias, const float* __restrict__ bias2,
                      void* __restrict__ C0, void* __restrict__ C1,
                      int M, int K, int N, int N0, int gx) {
    // bijective XCD swizzle (m204)
    int nwg = gridDim.x;
    int d = blockIdx.x;
    int q = nwg >> 3, r8 = nwg & 7;
    int xcd = d & 7, idx = d >> 3;
    int flat = (xcd < r8 ? xcd * (q + 1) : r8 * (q + 1) + (xcd - r8) * q) + idx;
    int bxt = flat % gx, byt = flat / gx;

    int tid = threadIdx.x;
    int wid = tid >> 6;        // 0..7
    int lane = tid & 63;
    int lr = lane & 15;        // row (A) / col (B) within fragment
    int lb = lane >> 4;        // k-chunk 0..3 (8 elems = 16 B each)
    int wr = wid >> 1;         // wave row 0..3 (M dir)
    int wc = wid & 1;          // wave col 0..1 (N dir)

    int bm = byt * 256;        // block row base
    int bn = bxt * 128;        // block col base

    // LDS: 3 buffers x [A 8192 u16 (256x32) | B 4096 u16 (128x32)] = 72 KB
    __shared__ u16 smem[3 * 12288];

    const int NT0 = K >> 5;                    // K-steps per stream
    const int NT = DUAL ? (NT0 * 2) : NT0;

    // ---- hoisted staging state (per thread: 2 A-chunks + 1 B-chunk) ----
    int c  = tid & 3;                          // 16B chunk-in-row
    int rr = tid >> 2;                         // staging row 0..127
    int cg = c ^ ((rr >> 1) & 3);              // 2-way-free source swizzle
    int rA0 = bm + rr;       if (rA0 > M - 1) rA0 = M - 1;
    int rA1 = bm + rr + 128; if (rA1 > M - 1) rA1 = M - 1;
    const u16* pA0 = A0 + (size_t)rA0 * K + cg * 8;
    const u16* pA1 = A0 + (size_t)rA1 * K + cg * 8;
    const u16* pB0 = W0T + (size_t)(bn + rr) * K + cg * 8;  // rr<128, bn+127<N
    int dA0 = tid * 8, dA1 = (tid + 512) * 8;  // A chunk LDS offsets (u16)
    int dB0 = 8192 + tid * 8;                  // B region starts at 8192 u16

    auto issue = [&](int buf) {
        u16* ab = smem + buf * 12288;
        __builtin_amdgcn_global_load_lds(
            (const __attribute__((address_space(1))) void*)pA0,
            (__attribute__((address_space(3))) void*)(ab + dA0), 16, 0, 0);
        __builtin_amdgcn_global_load_lds(
            (const __attribute__((address_space(1))) void*)pA1,
            (__attribute__((address_space(3))) void*)(ab + dA1), 16, 0, 0);
        __builtin_amdgcn_global_load_lds(
            (const __attribute__((address_space(1))) void*)pB0,
            (__attribute__((address_space(3))) void*)(ab + dB0), 16, 0, 0);
        pA0 += 32; pA1 += 32; pB0 += 32;
    };

    float4v acc[4][4] = {};

    // prologue: stage K-steps 0 and 1 into buffers 0 and 1 (NT >= 8 here)
    issue(0);
    issue(1);

    int sw = lb ^ ((lr >> 1) & 3);             // 2-way-free read swizzle
    int rdA = (wr * 64 + lr) * 32 + sw * 8;    // + i*512 per fragment (16 rows)
    int rdB = 8192 + (wc * 64 + lr) * 32 + sw * 8;

    for (int kt = 0; kt < NT; ++kt) {
        // counted vmcnt: wait only for the buffer we're about to read.
        if (kt + 1 < NT) asm volatile("s_waitcnt vmcnt(3)" ::: "memory");
        else             asm volatile("s_waitcnt vmcnt(0)" ::: "memory");
        __builtin_amdgcn_s_barrier();          // all waves' loads for this buf landed

        const u16* base = smem + (kt % 3) * 12288;
        short8v af[4], bf[4];
#pragma unroll
        for (int i = 0; i < 4; ++i)
            af[i] = *(const short8v*)(base + rdA + i * 512);
#pragma unroll
        for (int j = 0; j < 4; ++j)
            bf[j] = *(const short8v*)(base + rdB + j * 512);

        // stage K-step kt+2 into the buffer last read at iter kt-1
        if (kt + 2 < NT) {
            if (DUAL && kt + 2 == NT0) {       // stream seam: reset pointers
                pA0 = A1 + (size_t)rA0 * K + cg * 8;
                pA1 = A1 + (size_t)rA1 * K + cg * 8;
                pB0 = W1T + (size_t)(bn + rr) * K + cg * 8;
            }
            issue((kt + 2) % 3);
        }

        __builtin_amdgcn_s_setprio(1);
#pragma unroll
        for (int i = 0; i < 4; ++i)
#pragma unroll
            for (int j = 0; j < 4; ++j)
                acc[i][j] = __builtin_amdgcn_mfma_f32_16x16x32_bf16(
                    af[i], bf[j], acc[i][j], 0, 0, 0);
        __builtin_amdgcn_s_setprio(0);
    }

    // epilogue: C[bm + wr*64 + i*16 + lb*4 + rr2][bn + wc*64 + j*16 + lr]
    int bmw = bm + wr * 64, bnw = bn + wc * 64;
    if (EPI == 0) {
        float bi[4];
#pragma unroll
        for (int j = 0; j < 4; ++j) bi[j] = bias[bnw + j * 16 + lr];
#pragma unroll
        for (int i = 0; i < 4; ++i) {
#pragma unroll
            for (int rr2 = 0; rr2 < 4; ++rr2) {
                int row = bmw + i * 16 + lb * 4 + rr2;
                if (row >= M) continue;
#pragma unroll
                for (int j = 0; j < 4; ++j) {
                    int col = bnw + j * 16 + lr;
                    float v = acc[i][j][rr2] + bi[j];
                    v = (v > 0.0f) ? v : expm1f(v);
                    ((u16*)C0)[(size_t)row * N + col] = f2b(v);
                }
            }
        }
    } else if (EPI == 4) {
        // tiles never straddle N0 (N0 % 128 == 0)
        bool resTile = (bnw >= N0);
        int N1 = N - N0;
        float bi[4];
#pragma unroll
        for (int j = 0; j < 4; ++j) {
            int cidx = bnw + j * 16 + lr;
            bi[j] = resTile ? bias2[cidx - N0] : bias[cidx];
        }
#pragma unroll
        for (int i = 0; i < 4; ++i) {
#pragma unroll
            for (int rr2 = 0; rr2 < 4; ++rr2) {
                int row = bmw + i * 16 + lb * 4 + rr2;
                if (row >= M) continue;
#pragma unroll
                for (int j = 0; j < 4; ++j) {
                    int col = bnw + j * 16 + lr;
                    float v = acc[i][j][rr2] + bi[j];
                    v = (v > 0.0f) ? v : expm1f(v);
                    if (resTile) ((float*)C1)[(size_t)row * N1 + (col - N0)] = v;
                    else         ((u16*)C0)[(size_t)row * N0 + col] = f2b(v);
                }
            }
        }
    } else {
        int N1 = N - N0;
#pragma unroll
        for (int i = 0; i < 4; ++i) {
#pragma unroll
            for (int rr2 = 0; rr2 < 4; ++rr2) {
                int row = bmw + i * 16 + lb * 4 + rr2;
                if (row >= M) continue;
#pragma unroll
                for (int j = 0; j < 4; ++j) {
                    int col = bnw + j * 16 + lr;
                    float v = acc[i][j][rr2];
                    if (col < N0) {
                        ((u16*)C0)[(size_t)row * N0 + col] = f2b(v);
                    } else {
                        int c1 = col - N0;
                        if (EPI == 3) ((float*)C1)[(size_t)row * N1 + c1] = v;
                        else          ((u16*)C1)[(size_t)row * N1 + c1] = f2b(v);
                    }
                }
            }
        }
    }
}

// ---------------------------------------------------------------------------

extern "C" void kernel_launch(void* const* d_in, const int* in_sizes, int n_in,
                              void* d_out, int out_size, void* d_ws, size_t ws_size,
                              hipStream_t stream) {
    const float* features = (const float*)d_in[0];
    const int*   edge_src = (const int*)d_in[1];
    const int*   edge_dst = (const int*)d_in[2];
    const float* W1s = (const float*)d_in[3];
    const float* W1n = (const float*)d_in[4];
    const float* b1  = (const float*)d_in[5];
    const float* W2s = (const float*)d_in[6];
    const float* W2n = (const float*)d_in[7];
    const float* b2  = (const float*)d_in[8];
    const float* W3s = (const float*)d_in[9];
    const float* W3n = (const float*)d_in[10];
    const float* b3  = (const float*)d_in[11];
    const float* Wres = (const float*)d_in[12];
    const float* bres = (const float*)d_in[13];

    float* out_x   = (float*)d_out;
    float* out_res = out_x + (size_t)N_NODES * OUT_DIM;

    // ---- workspace layout ----
    size_t off = 0;
    auto carve = [&](size_t bytes) {
        size_t p = off;
        off += (bytes + 255) & ~(size_t)255;
        return p;
    };
    size_t o_cnt     = carve((size_t)N_NODES * 4);
    size_t o_rowptr  = carve((size_t)(N_NODES + 1) * 4);
    size_t o_cursor  = carve((size_t)N_NODES * 4);
    size_t o_invdeg  = carve((size_t)N_NODES * 4);
    size_t o_csr     = carve((size_t)N_EDGES * 4);
    size_t o_bsum    = carve((size_t)SCAN_NB * 4);
    size_t o_boff    = carve((size_t)SCAN_NB * 4);
    size_t o_w1   = carve((size_t)(H1 + OUT_DIM) * IN_DIM * 2);   // [W1s|Wres]T : 768 x 256
    size_t o_w1n  = carve((size_t)(H1 + OUT_DIM) * IN_DIM * 2);   // [W1n|0]T    : 768 x 256
    size_t o_w23  = carve((size_t)H1 * (H2 + H2) * 2);            // [W2n|W2s]T  : 640 x 640
    size_t o_w3   = carve((size_t)H2 * (OUT_DIM * 2) * 2);        // [W3n|W3s]T  : 256 x 320
    size_t o_regA = carve((size_t)N_NODES * (IN_DIM + IN_DIM) * 2);  // fX+aggF ; later x2
    size_t o_regB = carve((size_t)N_NODES * H1 * 2);                 // x1 ; later Y3+T3(f32)
    size_t o_regC = carve((size_t)N_NODES * H2 * 2);                 // Y2
    size_t o_regD = carve((size_t)N_NODES * H2 * 2);                 // T2
    size_t REQUIRED = off;
    if (ws_size < REQUIRED) return;

    char* W = (char*)d_ws;
    int*   cnt     = (int*)(W + o_cnt);
    int*   row_ptr = (int*)(W + o_rowptr);
    int*   cursor  = (int*)(W + o_cursor);
    float* inv_deg = (float*)(W + o_invdeg);
    int*   csr_src = (int*)(W + o_csr);
    int*   bsum    = (int*)(W + o_bsum);
    int*   boff    = (int*)(W + o_boff);
    u16* W1T  = (u16*)(W + o_w1);
    u16* W1nT = (u16*)(W + o_w1n);
    u16* W23T = (u16*)(W + o_w23);
    u16* W3T  = (u16*)(W + o_w3);
    u16* fX   = (u16*)(W + o_regA);
    u16* aggF = fX + (size_t)N_NODES * IN_DIM;
    u16* x2   = (u16*)(W + o_regA);                 // aliases fX+aggF (dead by then)
    u16* x1   = (u16*)(W + o_regB);
    u16* Y3   = (u16*)(W + o_regB);                 // aliases x1 (dead by then)
    float* T3 = (float*)(W + o_regB + (size_t)N_NODES * OUT_DIM * 2);
    u16* Y2   = (u16*)(W + o_regC);
    u16* T2   = (u16*)(W + o_regD);

    const int mt = (N_NODES + 255) / 256;   // 196 M-tiles of 256

    // ---- CSR build (multi-block scan) ----
    zero2_kernel<<<(N_NODES + 255) / 256, 256, 0, stream>>>(cnt, cursor, N_NODES);
    count_deg_kernel<<<(N_EDGES + 255) / 256, 256, 0, stream>>>(edge_dst, cnt, N_EDGES);
    block_sum_kernel<<<SCAN_NB, SCAN_BLK, 0, stream>>>(cnt, bsum);
    scan_bsum_kernel<<<1, SCAN_BLK, 0, stream>>>(bsum, boff);
    final_scan_kernel<<<SCAN_NB, SCAN_BLK, 0, stream>>>(cnt, boff, row_ptr, inv_deg);
    scatter_kernel<<<(N_EDGES + 255) / 256, 256, 0, stream>>>(edge_src, edge_dst, row_ptr,
                                                              cursor, csr_src, N_EDGES);

    // ---- casts / transposes ----
    {
        int n4 = N_NODES * IN_DIM / 4;
        cast_kernel<<<(n4 + 255) / 256, 256, 0, stream>>>((const float4*)features,
                                                          (ushort4*)fX, n4);
    }
    {
        // zero the [W1n|0] pad rows (rows 640..767 of W1nT: 128*256 u16 = 8192 ints)
        int* pad = (int*)(W1nT + (size_t)H1 * IN_DIM);
        zero2_kernel<<<(8192 + 255) / 256, 256, 0, stream>>>(pad, pad, 8192);
        dim3 b(32, 8), g(20, 20, 7);
        transpose_all_kernel<<<g, b, 0, stream>>>(W1s, Wres, W1n, W2n, W2s, W3n, W3s,
                                                  W1T, W1nT, W23T, W3T);
    }

    // ---- layer 1 + residual (merged):
    //   [x1|res] = elu( fX@[W1s|Wres] + aggF@[W1n|0] + [b1|bres] ) ----
    aggregate_kernel<IN_DIM, 0><<<AGG_GRID, 256, 0, stream>>>(
        fX, row_ptr, csr_src, inv_deg, nullptr, nullptr, aggF);
    mfma_gemm_kernel<true, 4><<<((H1 + OUT_DIM) / 128) * mt, 512, 0, stream>>>(
        fX, aggF, W1T, W1nT, b1, bres, x1, out_res,
        N_NODES, IN_DIM, H1 + OUT_DIM, H1, (H1 + OUT_DIM) / 128);

    // ---- layer 2: [Y2|T2] = x1@[W2n|W2s]; x2 = elu(mean(Y2) + T2 + b2) ----
    mfma_gemm_kernel<false, 2><<<((H2 * 2) / 128) * mt, 512, 0, stream>>>(
        x1, nullptr, W23T, nullptr, nullptr, nullptr, Y2, T2,
        N_NODES, H1, H2 * 2, H2, (H2 * 2) / 128);
    aggregate_kernel<H2, 1><<<AGG_GRID, 256, 0, stream>>>(
        Y2, row_ptr, csr_src, inv_deg, T2, b2, x2);

    // ---- layer 3: [Y3|T3] = x2@[W3n|W3s]; out_x = elu(mean(Y3) + T3 + b3) ----
    mfma_gemm_kernel<false, 3><<<((OUT_DIM * 2) / 128) * mt, 512, 0, stream>>>(
        x2, nullptr, W3T, nullptr, nullptr, nullptr, Y3, T3,
        N_NODES, H2, OUT_DIM * 2, OUT_DIM, (OUT_DIM * 2) / 128);
    aggregate_kernel<OUT_DIM, 2><<<AGG_GRID, 256, 0, stream>>>(
        Y3, row_ptr, csr_src, inv_deg, T3, b3, out_x);
}